// Round 6
// baseline (2007.560 us; speedup 1.0000x reference)
//
#include <hip/hip_runtime.h>
#include <hip/hip_fp16.h>
#include <math.h>

#define N_NODES 50000
#define N_EDGES 1600000
#define NFEAT 256
#define NHID 128
#define NCLASS 40

#define BSHIFT 6
#define BNODES 64            // nodes per bucket
#define NBUCK 782            // 50048 / 64
#define NPAD  50048          // NBUCK * BNODES (dummy rows >= N_NODES)
#define CAP   2560           // per-bucket edge capacity (mean 2048, +11 sigma)
#define EPB   4096           // edges per binA block -> 391 blocks

typedef _Float16 f16x8 __attribute__((ext_vector_type(8)));
typedef float f32x4 __attribute__((ext_vector_type(4)));

// ---------------- pass A: bucket edges by dst>>6, count per-node in-degree ----------------
__global__ __launch_bounds__(256) void k_binA(const int* __restrict__ src,
                                              const int* __restrict__ dst,
                                              int* __restrict__ gcur,
                                              int* __restrict__ deg,
                                              unsigned int* __restrict__ packed) {
    __shared__ int lhist[NBUCK];
    __shared__ int lbase[NBUCK];
    __shared__ int lcur[NBUCK];
    int t = threadIdx.x;
    for (int i = t; i < NBUCK; i += 256) { lhist[i] = 0; lcur[i] = 0; }
    __syncthreads();
    int e0 = blockIdx.x * EPB;
    int e1 = min(e0 + EPB, N_EDGES);
    for (int e = e0 + t; e < e1; e += 256) {
        int d = dst[e];
        atomicAdd(&lhist[d >> BSHIFT], 1);
        atomicAdd(&deg[d], 1);
    }
    __syncthreads();
    for (int i = t; i < NBUCK; i += 256)
        lbase[i] = atomicAdd(&gcur[i], lhist[i]);
    __syncthreads();
    for (int e = e0 + t; e < e1; e += 256) {
        int d = dst[e];
        int b = d >> BSHIFT;
        int r = atomicAdd(&lcur[b], 1);
        int pos = lbase[b] + r;
        if (pos < CAP)
            packed[(size_t)b * CAP + pos] =
                ((unsigned int)src[e] << BSHIFT) | (unsigned int)(d & (BNODES - 1));
    }
}

// ---------------- dinv from degree ----------------
__global__ __launch_bounds__(256) void k_dinv(const int* __restrict__ deg,
                                              float* __restrict__ dinv) {
    int t = blockIdx.x * 256 + threadIdx.x;
    if (t < NPAD) dinv[t] = (t < N_NODES) ? rsqrtf((float)(deg[t] + 1)) : 0.0f;
}

// ---------------- prep: W transposes to fp16 + zero gcur/deg ----------------
__global__ __launch_bounds__(256) void k_prep(const float* __restrict__ W1,
                                              const float* __restrict__ W2,
                                              __half* __restrict__ w1t,
                                              __half* __restrict__ w2t,
                                              int* __restrict__ gcur,
                                              int* __restrict__ deg) {
    int t = blockIdx.x * 256 + threadIdx.x;
    if (t < NBUCK) gcur[t] = 0;
    if (t < NPAD) deg[t] = 0;
    if (t < 128 * 256) {
        int n = t >> 8, k = t & 255;
        w1t[t] = __float2half(W1[k * NHID + n]);
    }
    if (t < 48 * 128) {
        int n = t >> 7, k = t & 127;
        w2t[t] = __float2half(n < NCLASS ? W2[k * NCLASS + n] : 0.0f);
    }
}

// ---------------- GEMM1 (MFMA): h1 planes[4][NPAD][32] = (x @ W1) * dinv[row] ----------------
#define G1_LDA 72
#define G1_LDB 72
#define G1_LDE 136
__global__ __launch_bounds__(256) void k_gemm1(const float* __restrict__ x,
                                               const __half* __restrict__ w1t,
                                               const float* __restrict__ dinv,
                                               __half* __restrict__ h1pl) {
    __shared__ __half smem[64 * G1_LDA + 128 * G1_LDB];   // 27.6 KB
    __half* sA = smem;
    __half* sB = smem + 64 * G1_LDA;
    int t = threadIdx.x;
    int rbase = blockIdx.x * 64;
    int lane = t & 63, wv = t >> 6;
    int m = lane & 15, quad = lane >> 4;
    f32x4 acc[8];
    #pragma unroll
    for (int i = 0; i < 8; i++) acc[i] = (f32x4)0.0f;

    int arow = t >> 2, aseg = t & 3;
    int grow = rbase + arow;
    bool avalid = grow < N_NODES;
    int bn = t >> 1, bseg = t & 1;

    for (int k0 = 0; k0 < NFEAT; k0 += 64) {
        const float4* gs = (const float4*)(x + (size_t)grow * NFEAT + k0 + aseg * 16);
        __half* ad = sA + arow * G1_LDA + aseg * 16;
        #pragma unroll
        for (int i = 0; i < 4; i++) {
            float4 v = avalid ? gs[i] : make_float4(0.f, 0.f, 0.f, 0.f);
            __half2 h0 = __float22half2_rn(make_float2(v.x, v.y));
            __half2 h1 = __float22half2_rn(make_float2(v.z, v.w));
            uint2 st;
            st.x = __builtin_bit_cast(unsigned int, h0);
            st.y = __builtin_bit_cast(unsigned int, h1);
            *(uint2*)(ad + i * 4) = st;
        }
        const uint4* ws4 = (const uint4*)(w1t + bn * NFEAT + k0 + bseg * 32);
        uint4* bd = (uint4*)(sB + bn * G1_LDB + bseg * 32);
        #pragma unroll
        for (int i = 0; i < 4; i++) bd[i] = ws4[i];
        __syncthreads();
        #pragma unroll
        for (int kk = 0; kk < 64; kk += 32) {
            f16x8 af = *(const f16x8*)(sA + (wv * 16 + m) * G1_LDA + kk + quad * 8);
            #pragma unroll
            for (int t8 = 0; t8 < 8; t8++) {
                f16x8 bf = *(const f16x8*)(sB + (t8 * 16 + m) * G1_LDB + kk + quad * 8);
                acc[t8] = __builtin_amdgcn_mfma_f32_16x16x32_f16(af, bf, acc[t8], 0, 0, 0);
            }
        }
        __syncthreads();
    }
    float di4[4];
    #pragma unroll
    for (int r = 0; r < 4; r++) di4[r] = dinv[rbase + wv * 16 + quad * 4 + r];
    __half* eb = smem;
    #pragma unroll
    for (int t8 = 0; t8 < 8; t8++) {
        #pragma unroll
        for (int r = 0; r < 4; r++)
            eb[(wv * 16 + quad * 4 + r) * G1_LDE + t8 * 16 + m] = __float2half(acc[t8][r] * di4[r]);
    }
    __syncthreads();
    {   // plane-major store: plane aseg holds features [aseg*32, +32) as 64B rows
        const uint4* es = (const uint4*)(eb + arow * G1_LDE + aseg * 32);
        uint4* od = (uint4*)(h1pl + (size_t)aseg * NPAD * 32 + (size_t)grow * 32);
        #pragma unroll
        for (int i = 0; i < 4; i++) od[i] = es[i];
    }
}

// ---------------- GEMM2 (MFMA): h2 planes = (h1p @ W2) * dinv[row] ----------------
#define G2_LDA 136
#define G2_LDB 136
#define G2_LDE 72
__global__ __launch_bounds__(256) void k_gemm2(const __half* __restrict__ h1p,
                                               const __half* __restrict__ w2t,
                                               const float* __restrict__ dinv,
                                               __half* __restrict__ h2pl) {
    __shared__ __half smem[64 * G2_LDA + 48 * G2_LDB];  // 30.5 KB
    __half* sA = smem;
    __half* sB = smem + 64 * G2_LDA;
    int t = threadIdx.x;
    int rbase = blockIdx.x * 64;
    int lane = t & 63, wv = t >> 6;
    int m = lane & 15, quad = lane >> 4;
    f32x4 acc[3];
    #pragma unroll
    for (int i = 0; i < 3; i++) acc[i] = (f32x4)0.0f;

    int arow = t >> 2, aseg = t & 3;
    int grow = rbase + arow;
    bool avalid = grow < N_NODES;

    #pragma unroll
    for (int i = 0; i < 3; i++) {
        int idx = t + i * 256;
        int n = idx >> 4, seg = idx & 15;
        *(uint4*)(sB + n * G2_LDB + seg * 8) = *(const uint4*)(w2t + n * NHID + seg * 8);
    }
    {
        const uint4* gs = (const uint4*)(h1p + (size_t)grow * NHID + aseg * 32);
        uint4* ad = (uint4*)(sA + arow * G2_LDA + aseg * 32);
        uint4 z; z.x = z.y = z.z = z.w = 0;
        #pragma unroll
        for (int i = 0; i < 4; i++) ad[i] = avalid ? gs[i] : z;
    }
    __syncthreads();
    #pragma unroll
    for (int kk = 0; kk < 128; kk += 32) {
        f16x8 af = *(const f16x8*)(sA + (wv * 16 + m) * G2_LDA + kk + quad * 8);
        #pragma unroll
        for (int t3 = 0; t3 < 3; t3++) {
            f16x8 bf = *(const f16x8*)(sB + (t3 * 16 + m) * G2_LDB + kk + quad * 8);
            acc[t3] = __builtin_amdgcn_mfma_f32_16x16x32_f16(af, bf, acc[t3], 0, 0, 0);
        }
    }
    __syncthreads();
    float di4[4];
    #pragma unroll
    for (int r = 0; r < 4; r++) di4[r] = dinv[rbase + wv * 16 + quad * 4 + r];
    __half* eb = smem;
    #pragma unroll
    for (int t3 = 0; t3 < 3; t3++) {
        #pragma unroll
        for (int r = 0; r < 4; r++)
            eb[(wv * 16 + quad * 4 + r) * G2_LDE + t3 * 16 + m] = __float2half(acc[t3][r] * di4[r]);
    }
    __syncthreads();
    // planeA: cls 0..31 (64B rows); planeB: cls 32..39 (16B rows); dummy rows are zeros (di=0)
    __half* pA = h2pl;
    __half* pB = h2pl + (size_t)NPAD * 32;
    #pragma unroll
    for (int i = 0; i < 2; i++) {
        int idx = t + i * 256;
        int row = idx >> 3, seg = idx & 7;
        int gr = rbase + row;
        if (seg <= 4) {
            uint4 v = *(const uint4*)(eb + row * G2_LDE + seg * 8);
            if (seg < 4) ((uint4*)pA)[(size_t)gr * 4 + seg] = v;
            else        ((uint4*)pB)[gr] = v;
        }
    }
}

// 8 halves (one 16B chunk) -> 8 fp32 LDS atomic adds
__device__ __forceinline__ void lds_acc8(float* a, uint4 v) {
    float2 f0 = __half22float2(__builtin_bit_cast(__half2, v.x));
    float2 f1 = __half22float2(__builtin_bit_cast(__half2, v.y));
    float2 f2 = __half22float2(__builtin_bit_cast(__half2, v.z));
    float2 f3 = __half22float2(__builtin_bit_cast(__half2, v.w));
    atomicAdd(a + 0, f0.x); atomicAdd(a + 1, f0.y);
    atomicAdd(a + 2, f1.x); atomicAdd(a + 3, f1.y);
    atomicAdd(a + 4, f2.x); atomicAdd(a + 5, f2.y);
    atomicAdd(a + 6, f3.x); atomicAdd(a + 7, f3.y);
}

// ---------------- agg1: bucket-parallel LDS scatter over one L2-resident feature plane ----------------
// block = one 64-node bucket; 4 lanes/edge (16B chunks); 64 edges in flight, unroll 2
__global__ __launch_bounds__(256) void k_agg1(int s,
                                              const __half* __restrict__ h1pl,
                                              const float* __restrict__ dinv,
                                              const unsigned int* __restrict__ packed,
                                              const int* __restrict__ gcur,
                                              const float* __restrict__ b1,
                                              const float* __restrict__ mask,
                                              __half* __restrict__ h1p) {
    __shared__ float accw[BNODES][33];   // stride-33 pad: banks spread by node
    int b = blockIdx.x, t = threadIdx.x;
    float* af = &accw[0][0];
    for (int i = t; i < BNODES * 33; i += 256) af[i] = 0.f;
    __syncthreads();
    const uint4* hp = (const uint4*)(h1pl + (size_t)s * NPAD * 32);
    int bcnt = min(gcur[b], CAP);
    const unsigned int* pk = packed + (size_t)b * CAP;
    int eg = t >> 2, c = t & 3;
    for (int base = 0; base < bcnt; base += 128) {
        int i0 = base + eg, i1 = i0 + 64;
        bool v0 = i0 < bcnt, v1 = i1 < bcnt;
        unsigned int w0 = 0, w1 = 0;
        uint4 g0, g1;
        if (v0) { w0 = pk[i0]; g0 = hp[(size_t)(w0 >> BSHIFT) * 4 + c]; }
        if (v1) { w1 = pk[i1]; g1 = hp[(size_t)(w1 >> BSHIFT) * 4 + c]; }
        if (v0) lds_acc8(&accw[w0 & (BNODES - 1)][c * 8], g0);
        if (v1) lds_acc8(&accw[w1 & (BNODES - 1)][c * 8], g1);
    }
    __syncthreads();
    int n = t >> 2;
    int node = b * BNODES + n;
    if (node < N_NODES) {
        float di = dinv[node];
        uint4 sv = hp[(size_t)node * 4 + c];            // self row (pre-scaled)
        float2 s0 = __half22float2(__builtin_bit_cast(__half2, sv.x));
        float2 s1 = __half22float2(__builtin_bit_cast(__half2, sv.y));
        float2 s2 = __half22float2(__builtin_bit_cast(__half2, sv.z));
        float2 s3 = __half22float2(__builtin_bit_cast(__half2, sv.w));
        const float* ar = &accw[n][c * 8];
        float a0 = ar[0] + s0.x, a1 = ar[1] + s0.y;
        float a2 = ar[2] + s1.x, a3 = ar[3] + s1.y;
        float a4 = ar[4] + s2.x, a5 = ar[5] + s2.y;
        float a6 = ar[6] + s3.x, a7 = ar[7] + s3.y;
        const float4* bp = (const float4*)(b1 + s * 32 + c * 8);
        float4 bb0 = bp[0], bb1 = bp[1];
        const float4* mp = (const float4*)(mask + (size_t)node * NHID + s * 32 + c * 8);
        float4 mm0 = mp[0], mm1 = mp[1];
        float o0 = fmaxf(fmaf(a0, di, bb0.x), 0.f) * mm0.x;
        float o1 = fmaxf(fmaf(a1, di, bb0.y), 0.f) * mm0.y;
        float o2 = fmaxf(fmaf(a2, di, bb0.z), 0.f) * mm0.z;
        float o3 = fmaxf(fmaf(a3, di, bb0.w), 0.f) * mm0.w;
        float o4 = fmaxf(fmaf(a4, di, bb1.x), 0.f) * mm1.x;
        float o5 = fmaxf(fmaf(a5, di, bb1.y), 0.f) * mm1.y;
        float o6 = fmaxf(fmaf(a6, di, bb1.z), 0.f) * mm1.z;
        float o7 = fmaxf(fmaf(a7, di, bb1.w), 0.f) * mm1.w;
        __half2 p0 = __float22half2_rn(make_float2(o0, o1));
        __half2 p1 = __float22half2_rn(make_float2(o2, o3));
        __half2 p2 = __float22half2_rn(make_float2(o4, o5));
        __half2 p3 = __float22half2_rn(make_float2(o6, o7));
        uint4 st;
        st.x = __builtin_bit_cast(unsigned int, p0);
        st.y = __builtin_bit_cast(unsigned int, p1);
        st.z = __builtin_bit_cast(unsigned int, p2);
        st.w = __builtin_bit_cast(unsigned int, p3);
        *(uint4*)(h1p + (size_t)node * NHID + s * 32 + c * 8) = st;
    }
}

// ---------------- agg2: bucket scatter over h2 planes + bias + log_softmax ----------------
__global__ __launch_bounds__(256) void k_agg2(const __half* __restrict__ h2pl,
                                              const float* __restrict__ dinv,
                                              const unsigned int* __restrict__ packed,
                                              const int* __restrict__ gcur,
                                              const float* __restrict__ b2,
                                              float* __restrict__ out) {
    __shared__ float accA[BNODES][33];   // cls 0..31
    __shared__ float accB[BNODES][9];    // cls 32..39
    int b = blockIdx.x, t = threadIdx.x;
    float* aa = &accA[0][0];
    for (int i = t; i < BNODES * 33; i += 256) aa[i] = 0.f;
    float* ab = &accB[0][0];
    for (int i = t; i < BNODES * 9; i += 256) ab[i] = 0.f;
    __syncthreads();
    const uint4* pA = (const uint4*)h2pl;                              // [NPAD] x 4 chunks
    const uint4* pB = (const uint4*)(h2pl + (size_t)NPAD * 32);        // [NPAD] x 1 chunk
    int bcnt = min(gcur[b], CAP);
    const unsigned int* pk = packed + (size_t)b * CAP;
    int eg = t >> 2, c = t & 3;
    for (int base = 0; base < bcnt; base += 128) {     // plane A: 4 lanes/edge
        int i0 = base + eg, i1 = i0 + 64;
        bool v0 = i0 < bcnt, v1 = i1 < bcnt;
        unsigned int w0 = 0, w1 = 0;
        uint4 g0, g1;
        if (v0) { w0 = pk[i0]; g0 = pA[(size_t)(w0 >> BSHIFT) * 4 + c]; }
        if (v1) { w1 = pk[i1]; g1 = pA[(size_t)(w1 >> BSHIFT) * 4 + c]; }
        if (v0) lds_acc8(&accA[w0 & (BNODES - 1)][c * 8], g0);
        if (v1) lds_acc8(&accA[w1 & (BNODES - 1)][c * 8], g1);
    }
    for (int base = 0; base < bcnt; base += 512) {     // plane B: 1 lane/edge
        int i0 = base + t, i1 = i0 + 256;
        if (i0 < bcnt) {
            unsigned int w = pk[i0];
            uint4 g = pB[w >> BSHIFT];
            lds_acc8(&accB[w & (BNODES - 1)][0], g);
        }
        if (i1 < bcnt) {
            unsigned int w = pk[i1];
            uint4 g = pB[w >> BSHIFT];
            lds_acc8(&accB[w & (BNODES - 1)][0], g);
        }
    }
    __syncthreads();
    if (t < BNODES) {
        int node = b * BNODES + t;
        if (node < N_NODES) {
            float di = dinv[node];
            float val[40];
            #pragma unroll
            for (int k = 0; k < 4; k++) {
                uint4 sv = pA[(size_t)node * 4 + k];
                float2 f0 = __half22float2(__builtin_bit_cast(__half2, sv.x));
                float2 f1 = __half22float2(__builtin_bit_cast(__half2, sv.y));
                float2 f2 = __half22float2(__builtin_bit_cast(__half2, sv.z));
                float2 f3 = __half22float2(__builtin_bit_cast(__half2, sv.w));
                val[k * 8 + 0] = accA[t][k * 8 + 0] + f0.x;
                val[k * 8 + 1] = accA[t][k * 8 + 1] + f0.y;
                val[k * 8 + 2] = accA[t][k * 8 + 2] + f1.x;
                val[k * 8 + 3] = accA[t][k * 8 + 3] + f1.y;
                val[k * 8 + 4] = accA[t][k * 8 + 4] + f2.x;
                val[k * 8 + 5] = accA[t][k * 8 + 5] + f2.y;
                val[k * 8 + 6] = accA[t][k * 8 + 6] + f3.x;
                val[k * 8 + 7] = accA[t][k * 8 + 7] + f3.y;
            }
            {
                uint4 sv = pB[node];
                float2 f0 = __half22float2(__builtin_bit_cast(__half2, sv.x));
                float2 f1 = __half22float2(__builtin_bit_cast(__half2, sv.y));
                float2 f2 = __half22float2(__builtin_bit_cast(__half2, sv.z));
                float2 f3 = __half22float2(__builtin_bit_cast(__half2, sv.w));
                val[32] = accB[t][0] + f0.x; val[33] = accB[t][1] + f0.y;
                val[34] = accB[t][2] + f1.x; val[35] = accB[t][3] + f1.y;
                val[36] = accB[t][4] + f2.x; val[37] = accB[t][5] + f2.y;
                val[38] = accB[t][6] + f3.x; val[39] = accB[t][7] + f3.y;
            }
            #pragma unroll
            for (int k = 0; k < 40; k++) val[k] = fmaf(val[k], di, b2[k]);
            float m = val[0];
            #pragma unroll
            for (int k = 1; k < 40; k++) m = fmaxf(m, val[k]);
            float ssum = 0.f;
            #pragma unroll
            for (int k = 0; k < 40; k++) ssum += expf(val[k] - m);
            float ls = m + logf(ssum);
            float4* orow = (float4*)(out + (size_t)node * NCLASS);
            #pragma unroll
            for (int k = 0; k < 10; k++)
                orow[k] = make_float4(val[4 * k] - ls, val[4 * k + 1] - ls,
                                      val[4 * k + 2] - ls, val[4 * k + 3] - ls);
        }
    }
}

extern "C" void kernel_launch(void* const* d_in, const int* in_sizes, int n_in,
                              void* d_out, int out_size, void* d_ws, size_t ws_size,
                              hipStream_t stream) {
    const float* x    = (const float*)d_in[0];
    const int*   ei   = (const int*)d_in[1];
    const float* W1   = (const float*)d_in[2];
    const float* b1   = (const float*)d_in[3];
    const float* W2   = (const float*)d_in[4];
    const float* b2   = (const float*)d_in[5];
    const float* mask = (const float*)d_in[6];
    float* out = (float*)d_out;

    const int* src = ei;
    const int* dst = ei + N_EDGES;

    char* ws = (char*)d_ws;
    size_t off = 0;
    __half* h1p    = (__half*)(ws + off); off += (size_t)NPAD * NHID * 2;        // 12.8 MB
    __half* h1pl   = (__half*)(ws + off); off += (size_t)4 * NPAD * 32 * 2;      // 12.8 MB (4 feature planes)
    unsigned int* packed = (unsigned int*)(ws + off); off += (size_t)NBUCK * CAP * 4;  // 8.0 MB
    int*    deg    = (int*)   (ws + off); off += (size_t)NPAD * 4;
    float*  dinv   = (float*) (ws + off); off += (size_t)NPAD * 4;
    int*    gcur   = (int*)   (ws + off); off += 4096;
    __half* w1t    = (__half*)(ws + off); off += 128 * 256 * 2;                  // 64 KB
    __half* w2t    = (__half*)(ws + off); off += 48 * 128 * 2;                   // 12 KB

    __half* h2pl = h1pl;   // gemm2/agg2 lifetime: planeA 3.2MB + planeB 0.8MB reuse plane space

    k_prep<<<196, 256, 0, stream>>>(W1, W2, w1t, w2t, gcur, deg);
    k_binA<<<(N_EDGES + EPB - 1) / EPB, 256, 0, stream>>>(src, dst, gcur, deg, packed);
    k_dinv<<<196, 256, 0, stream>>>(deg, dinv);

    k_gemm1<<<NPAD / 64, 256, 0, stream>>>(x, w1t, dinv, h1pl);
    for (int s = 0; s < 4; s++)
        k_agg1<<<NBUCK, 256, 0, stream>>>(s, h1pl, dinv, packed, gcur, b1, mask, h1p);
    k_gemm2<<<NPAD / 64, 256, 0, stream>>>(h1p, w2t, dinv, h2pl);
    k_agg2<<<NBUCK, 256, 0, stream>>>(h2pl, dinv, packed, gcur, b2, out);
}

// Round 7
// 326.398 us; speedup vs baseline: 6.1506x; 6.1506x over previous
//
#include <hip/hip_runtime.h>
#include <hip/hip_fp16.h>
#include <math.h>

#define N_NODES 50000
#define N_EDGES 1600000
#define NFEAT 256
#define NHID 128
#define NCLASS 40

#define NPAD 50048           // grid-rounded node count (dummy zero rows >= N_NODES)
#define DUMMY N_NODES        // index of a guaranteed-zero table row

#define BSHIFT 7
#define NBUCK 391            // ceil(50000 / 128)
#define CAP 5120             // per-bucket capacity (mean 4092)
#define EPB 4096             // edges per binA block -> 391 blocks

typedef _Float16 f16x8 __attribute__((ext_vector_type(8)));
typedef float f32x4 __attribute__((ext_vector_type(4)));

// ---------------- pass A: coarse binning by dst>>7 + global in-degree count ----------------
__global__ __launch_bounds__(256) void k_binA(const int* __restrict__ src,
                                              const int* __restrict__ dst,
                                              int* __restrict__ gcur,
                                              int* __restrict__ deg,
                                              unsigned int* __restrict__ packed) {
    __shared__ int lhist[NBUCK];
    __shared__ int lbase[NBUCK];
    __shared__ int lcur[NBUCK];
    int t = threadIdx.x;
    for (int i = t; i < NBUCK; i += 256) { lhist[i] = 0; lcur[i] = 0; }
    __syncthreads();
    int e0 = blockIdx.x * EPB;
    int e1 = min(e0 + EPB, N_EDGES);
    for (int e = e0 + t; e < e1; e += 256) {
        int d = dst[e];
        atomicAdd(&lhist[d >> BSHIFT], 1);
        atomicAdd(&deg[d], 1);
    }
    __syncthreads();
    for (int i = t; i < NBUCK; i += 256)
        lbase[i] = atomicAdd(&gcur[i], lhist[i]);
    __syncthreads();
    for (int e = e0 + t; e < e1; e += 256) {
        int d = dst[e];
        int b = d >> BSHIFT;
        int r = atomicAdd(&lcur[b], 1);
        int pos = lbase[b] + r;
        if (pos < CAP)
            packed[(size_t)b * CAP + pos] =
                ((unsigned int)src[e] << BSHIFT) | (unsigned int)(d & 127);
    }
}

// ---------------- dinv from degree (dummy rows -> 0 so their table rows are zeros) ----------------
__global__ __launch_bounds__(256) void k_dinv(const int* __restrict__ deg,
                                              float* __restrict__ dinv) {
    int t = blockIdx.x * 256 + threadIdx.x;
    if (t < NPAD) dinv[t] = (t < N_NODES) ? rsqrtf((float)(deg[t] + 1)) : 0.0f;
}

// ---------------- prep: W transposes to fp16 + zero gcur/deg ----------------
__global__ __launch_bounds__(256) void k_prep(const float* __restrict__ W1,
                                              const float* __restrict__ W2,
                                              __half* __restrict__ w1t,
                                              __half* __restrict__ w2t,
                                              int* __restrict__ gcur,
                                              int* __restrict__ deg) {
    int t = blockIdx.x * 256 + threadIdx.x;
    if (t < NBUCK) gcur[t] = 0;
    if (t < NPAD) deg[t] = 0;
    if (t < 128 * 256) {
        int n = t >> 8, k = t & 255;
        w1t[t] = __float2half(W1[k * NHID + n]);
    }
    if (t < 48 * 128) {
        int n = t >> 7, k = t & 127;
        w2t[t] = __float2half(n < NCLASS ? W2[k * NCLASS + n] : 0.0f);
    }
}

// ---------------- FUSED: blocks [0,NBUCK) = binB fine-sort; blocks [NBUCK, +782) = GEMM1 ----------------
#define G1_LDA 72
#define G1_LDB 72
#define G1_LDE 136
#define FUSE_BLOCKS (NBUCK + NPAD / 64)
__global__ __launch_bounds__(256) void k_fused(const int* __restrict__ gcur,
                                               const unsigned int* __restrict__ packed,
                                               int* __restrict__ esrc,
                                               int* __restrict__ row_beg,
                                               int* __restrict__ row_cnt,
                                               const float* __restrict__ x,
                                               const __half* __restrict__ w1t,
                                               const float* __restrict__ dinv,
                                               __half* __restrict__ h1h) {
    __shared__ __align__(16) char smem[27648];
    int t = threadIdx.x;
    if (blockIdx.x < NBUCK) {
        // ---- binB: in-LDS fine sort per bucket + CSR metadata ----
        unsigned int* sp = (unsigned int*)smem;          // 20480 B
        int* hist = (int*)(smem + 20480);                // 512 B
        int* scan = (int*)(smem + 20992);                // 512 B
        int* cur  = (int*)(smem + 21504);                // 512 B
        int b = blockIdx.x;
        int cnt = min(gcur[b], CAP);
        if (t < 128) { hist[t] = 0; cur[t] = 0; }
        __syncthreads();
        const unsigned int* pin = packed + (size_t)b * CAP;
        for (int i = t; i < cnt; i += 256) {
            unsigned int w = pin[i];
            sp[i] = w;
            atomicAdd(&hist[w & 127], 1);
        }
        __syncthreads();
        if (t == 0) {
            int s = 0;
            for (int i = 0; i < 128; i++) { scan[i] = s; s += hist[i]; }
        }
        __syncthreads();
        for (int i = t; i < cnt; i += 256) {
            unsigned int w = sp[i];
            int dl = (int)(w & 127u);
            int r = atomicAdd(&cur[dl], 1);
            esrc[(size_t)b * CAP + scan[dl] + r] = (int)(w >> BSHIFT);
        }
        if (t < 128) {
            int node = b * 128 + t;
            if (node < N_NODES) {
                row_beg[node] = b * CAP + scan[t];
                row_cnt[node] = hist[t];
            }
        }
    } else {
        // ---- GEMM1: h1h(fp16) = (x @ W1) * dinv[row] ----
        __half* sA = (__half*)smem;                      // 64*72*2 = 9216 B
        __half* sB = (__half*)(smem) + 64 * G1_LDA;      // 128*72*2 = 18432 B
        int rbase = (blockIdx.x - NBUCK) * 64;
        int lane = t & 63, wv = t >> 6;
        int m = lane & 15, quad = lane >> 4;
        f32x4 acc[8];
        #pragma unroll
        for (int i = 0; i < 8; i++) acc[i] = (f32x4)0.0f;

        int arow = t >> 2, aseg = t & 3;
        int grow = rbase + arow;
        bool avalid = grow < N_NODES;
        int bn = t >> 1, bseg = t & 1;

        for (int k0 = 0; k0 < NFEAT; k0 += 64) {
            const float4* gs = (const float4*)(x + (size_t)grow * NFEAT + k0 + aseg * 16);
            __half* ad = sA + arow * G1_LDA + aseg * 16;
            #pragma unroll
            for (int i = 0; i < 4; i++) {
                float4 v = avalid ? gs[i] : make_float4(0.f, 0.f, 0.f, 0.f);
                __half2 h0 = __float22half2_rn(make_float2(v.x, v.y));
                __half2 h1 = __float22half2_rn(make_float2(v.z, v.w));
                uint2 st;
                st.x = __builtin_bit_cast(unsigned int, h0);
                st.y = __builtin_bit_cast(unsigned int, h1);
                *(uint2*)(ad + i * 4) = st;
            }
            const uint4* ws4 = (const uint4*)(w1t + bn * NFEAT + k0 + bseg * 32);
            uint4* bd = (uint4*)(sB + bn * G1_LDB + bseg * 32);
            #pragma unroll
            for (int i = 0; i < 4; i++) bd[i] = ws4[i];
            __syncthreads();
            #pragma unroll
            for (int kk = 0; kk < 64; kk += 32) {
                f16x8 af = *(const f16x8*)(sA + (wv * 16 + m) * G1_LDA + kk + quad * 8);
                #pragma unroll
                for (int t8 = 0; t8 < 8; t8++) {
                    f16x8 bf = *(const f16x8*)(sB + (t8 * 16 + m) * G1_LDB + kk + quad * 8);
                    acc[t8] = __builtin_amdgcn_mfma_f32_16x16x32_f16(af, bf, acc[t8], 0, 0, 0);
                }
            }
            __syncthreads();
        }
        float di4[4];
        #pragma unroll
        for (int r = 0; r < 4; r++) di4[r] = dinv[rbase + wv * 16 + quad * 4 + r];
        __half* eb = (__half*)smem;
        #pragma unroll
        for (int t8 = 0; t8 < 8; t8++) {
            #pragma unroll
            for (int r = 0; r < 4; r++)
                eb[(wv * 16 + quad * 4 + r) * G1_LDE + t8 * 16 + m] = __float2half(acc[t8][r] * di4[r]);
        }
        __syncthreads();
        {   // unconditional store: dummy rows are zeros (dinv=0)
            const uint4* es = (const uint4*)(eb + arow * G1_LDE + aseg * 32);
            uint4* od = (uint4*)(h1h + (size_t)grow * NHID + aseg * 32);
            #pragma unroll
            for (int i = 0; i < 4; i++) od[i] = es[i];
        }
    }
}

// ---------------- GEMM2 (MFMA): h2 planes = (h1p @ W2) * dinv[row] ----------------
// planeA: cls 0..31 as 64B rows (3.2MB); planeB: cls 32..39 as 16B rows (0.8MB)
#define G2_LDA 136
#define G2_LDB 136
#define G2_LDE 72
__global__ __launch_bounds__(256) void k_gemm2(const __half* __restrict__ h1p,
                                               const __half* __restrict__ w2t,
                                               const float* __restrict__ dinv,
                                               __half* __restrict__ h2pl) {
    __shared__ __half smem[64 * G2_LDA + 48 * G2_LDB];  // 30.5 KB
    __half* sA = smem;
    __half* sB = smem + 64 * G2_LDA;
    int t = threadIdx.x;
    int rbase = blockIdx.x * 64;
    int lane = t & 63, wv = t >> 6;
    int m = lane & 15, quad = lane >> 4;
    f32x4 acc[3];
    #pragma unroll
    for (int i = 0; i < 3; i++) acc[i] = (f32x4)0.0f;

    int arow = t >> 2, aseg = t & 3;
    int grow = rbase + arow;
    bool avalid = grow < N_NODES;

    #pragma unroll
    for (int i = 0; i < 3; i++) {
        int idx = t + i * 256;
        int n = idx >> 4, seg = idx & 15;
        *(uint4*)(sB + n * G2_LDB + seg * 8) = *(const uint4*)(w2t + n * NHID + seg * 8);
    }
    {
        const uint4* gs = (const uint4*)(h1p + (size_t)grow * NHID + aseg * 32);
        uint4* ad = (uint4*)(sA + arow * G2_LDA + aseg * 32);
        uint4 z; z.x = z.y = z.z = z.w = 0;
        #pragma unroll
        for (int i = 0; i < 4; i++) ad[i] = avalid ? gs[i] : z;
    }
    __syncthreads();
    #pragma unroll
    for (int kk = 0; kk < 128; kk += 32) {
        f16x8 af = *(const f16x8*)(sA + (wv * 16 + m) * G2_LDA + kk + quad * 8);
        #pragma unroll
        for (int t3 = 0; t3 < 3; t3++) {
            f16x8 bf = *(const f16x8*)(sB + (t3 * 16 + m) * G2_LDB + kk + quad * 8);
            acc[t3] = __builtin_amdgcn_mfma_f32_16x16x32_f16(af, bf, acc[t3], 0, 0, 0);
        }
    }
    __syncthreads();
    float di4[4];
    #pragma unroll
    for (int r = 0; r < 4; r++) di4[r] = dinv[rbase + wv * 16 + quad * 4 + r];
    __half* eb = smem;
    #pragma unroll
    for (int t3 = 0; t3 < 3; t3++) {
        #pragma unroll
        for (int r = 0; r < 4; r++)
            eb[(wv * 16 + quad * 4 + r) * G2_LDE + t3 * 16 + m] = __float2half(acc[t3][r] * di4[r]);
    }
    __syncthreads();
    __half* pA = h2pl;
    __half* pB = h2pl + (size_t)NPAD * 32;
    #pragma unroll
    for (int i = 0; i < 2; i++) {
        int idx = t + i * 256;
        int row = idx >> 3, seg = idx & 7;
        int gr = rbase + row;   // unconditional: dummy rows store zeros (acc*0)
        if (seg <= 4) {
            uint4 v = *(const uint4*)(eb + row * G2_LDE + seg * 8);
            if (seg < 4) ((uint4*)pA)[(size_t)gr * 4 + seg] = v;
            else        ((uint4*)pB)[gr] = v;
        }
    }
}

__device__ __forceinline__ void acc8f(float* acc, uint4 v, float d) {
    float2 a0 = __half22float2(__builtin_bit_cast(__half2, v.x));
    float2 a1 = __half22float2(__builtin_bit_cast(__half2, v.y));
    float2 a2 = __half22float2(__builtin_bit_cast(__half2, v.z));
    float2 a3 = __half22float2(__builtin_bit_cast(__half2, v.w));
    acc[0] = fmaf(a0.x, d, acc[0]); acc[1] = fmaf(a0.y, d, acc[1]);
    acc[2] = fmaf(a1.x, d, acc[2]); acc[3] = fmaf(a1.y, d, acc[3]);
    acc[4] = fmaf(a2.x, d, acc[4]); acc[5] = fmaf(a2.y, d, acc[5]);
    acc[6] = fmaf(a3.x, d, acc[6]); acc[7] = fmaf(a3.y, d, acc[7]);
}

// ---------------- agg1: round-5 structure (UNCHANGED, 53 us control) ----------------
__global__ __launch_bounds__(64) void k_agg1(const __half* __restrict__ h1h,
                                             const float* __restrict__ dinv,
                                             const int* __restrict__ row_beg,
                                             const int* __restrict__ row_cnt,
                                             const int* __restrict__ esrc,
                                             const float* __restrict__ b1,
                                             const float* __restrict__ mask,
                                             __half* __restrict__ h1p) {
    int i = blockIdx.x;
    int lane = threadIdx.x;
    int q = lane >> 4;
    int fl = lane & 15;
    const uint4* hv4 = (const uint4*)h1h;
    float di = dinv[i];
    __half2 hacc[4];
    __half2 hz = __half2half2(__float2half(0.0f));
    hacc[0] = hz; hacc[1] = hz; hacc[2] = hz; hacc[3] = hz;
    int s0 = row_beg[i], cnt = row_cnt[i];
    for (int base = 0; base < cnt; base += 64) {
        int idx = base + lane;
        int sv = (idx < cnt) ? esrc[s0 + idx] : DUMMY;   // dummy row = zeros
        int n = min(64, cnt - base);
        int nr = (n + 31) & ~31;
        for (int j = 0; j < nr; j += 32) {
            int ss[8]; uint4 vv[8];
            #pragma unroll
            for (int k = 0; k < 8; k++) ss[k] = __shfl(sv, j + 4 * k + q);
            #pragma unroll
            for (int k = 0; k < 8; k++) vv[k] = hv4[(size_t)ss[k] * 16 + fl];
            #pragma unroll
            for (int k = 0; k < 8; k++) {
                hacc[0] = __hadd2(hacc[0], __builtin_bit_cast(__half2, vv[k].x));
                hacc[1] = __hadd2(hacc[1], __builtin_bit_cast(__half2, vv[k].y));
                hacc[2] = __hadd2(hacc[2], __builtin_bit_cast(__half2, vv[k].z));
                hacc[3] = __hadd2(hacc[3], __builtin_bit_cast(__half2, vv[k].w));
            }
        }
    }
    #pragma unroll
    for (int d = 16; d <= 32; d <<= 1) {
        #pragma unroll
        for (int r = 0; r < 4; r++) {
            unsigned int u = __shfl_xor(__builtin_bit_cast(unsigned int, hacc[r]), d);
            hacc[r] = __hadd2(hacc[r], __builtin_bit_cast(__half2, u));
        }
    }
    if (q == 0) {
        float acc[8];
        #pragma unroll
        for (int r = 0; r < 4; r++) {
            float2 f = __half22float2(hacc[r]);
            acc[2 * r] = f.x; acc[2 * r + 1] = f.y;
        }
        uint4 sv4 = hv4[(size_t)i * 16 + fl];      // self row (already *dinv[i])
        acc8f(acc, sv4, 1.0f);
        float4 bb0 = ((const float4*)b1)[fl * 2];
        float4 bb1 = ((const float4*)b1)[fl * 2 + 1];
        const float4* mrow = (const float4*)(mask + (size_t)i * NHID);
        float4 mm0 = mrow[fl * 2];
        float4 mm1 = mrow[fl * 2 + 1];
        float o0 = fmaxf(fmaf(acc[0], di, bb0.x), 0.f) * mm0.x;
        float o1 = fmaxf(fmaf(acc[1], di, bb0.y), 0.f) * mm0.y;
        float o2 = fmaxf(fmaf(acc[2], di, bb0.z), 0.f) * mm0.z;
        float o3 = fmaxf(fmaf(acc[3], di, bb0.w), 0.f) * mm0.w;
        float o4 = fmaxf(fmaf(acc[4], di, bb1.x), 0.f) * mm1.x;
        float o5 = fmaxf(fmaf(acc[5], di, bb1.y), 0.f) * mm1.y;
        float o6 = fmaxf(fmaf(acc[6], di, bb1.z), 0.f) * mm1.z;
        float o7 = fmaxf(fmaf(acc[7], di, bb1.w), 0.f) * mm1.w;
        __half2 p0 = __float22half2_rn(make_float2(o0, o1));
        __half2 p1 = __float22half2_rn(make_float2(o2, o3));
        __half2 p2 = __float22half2_rn(make_float2(o4, o5));
        __half2 p3 = __float22half2_rn(make_float2(o6, o7));
        uint4 st;
        st.x = __builtin_bit_cast(unsigned int, p0);
        st.y = __builtin_bit_cast(unsigned int, p1);
        st.z = __builtin_bit_cast(unsigned int, p2);
        st.w = __builtin_bit_cast(unsigned int, p3);
        ((uint4*)h1p)[(size_t)i * 16 + fl] = st;
    }
}

// ---------------- agg2: slim planes (64B + 16B rows), wave-per-node, + log_softmax ----------------
__global__ __launch_bounds__(64) void k_agg2(const __half* __restrict__ h2pl,
                                             const float* __restrict__ dinv,
                                             const int* __restrict__ row_beg,
                                             const int* __restrict__ row_cnt,
                                             const int* __restrict__ esrc,
                                             const float* __restrict__ b2,
                                             float* __restrict__ out) {
    int i = blockIdx.x;
    int lane = threadIdx.x;
    int g = lane >> 2;        // 16 edge groups
    int fl = lane & 3;        // 16B chunk of 64B planeA row
    const uint4* pA = (const uint4*)h2pl;
    const uint4* pB = (const uint4*)(h2pl + (size_t)NPAD * 32);
    float di = dinv[i];
    __half2 a0[4], a1[4];
    __half2 hz = __half2half2(__float2half(0.0f));
    #pragma unroll
    for (int r = 0; r < 4; r++) { a0[r] = hz; a1[r] = hz; }
    int s0 = row_beg[i], cnt = row_cnt[i];
    for (int base = 0; base < cnt; base += 64) {
        int idx = base + lane;
        int sv = (idx < cnt) ? esrc[s0 + idx] : DUMMY;
        // planeB: one edge per lane (16B row, zeros at DUMMY)
        uint4 v1 = pB[sv];
        a1[0] = __hadd2(a1[0], __builtin_bit_cast(__half2, v1.x));
        a1[1] = __hadd2(a1[1], __builtin_bit_cast(__half2, v1.y));
        a1[2] = __hadd2(a1[2], __builtin_bit_cast(__half2, v1.z));
        a1[3] = __hadd2(a1[3], __builtin_bit_cast(__half2, v1.w));
        // planeA: 16 groups x depth 2 => 32 edges per j-step
        int n = min(64, cnt - base);
        int nr = (n + 31) & ~31;
        for (int j = 0; j < nr; j += 32) {
            int ss[2]; uint4 vv[2];
            #pragma unroll
            for (int k = 0; k < 2; k++) ss[k] = __shfl(sv, j + 16 * k + g);
            #pragma unroll
            for (int k = 0; k < 2; k++) vv[k] = pA[(size_t)ss[k] * 4 + fl];
            #pragma unroll
            for (int k = 0; k < 2; k++) {
                a0[0] = __hadd2(a0[0], __builtin_bit_cast(__half2, vv[k].x));
                a0[1] = __hadd2(a0[1], __builtin_bit_cast(__half2, vv[k].y));
                a0[2] = __hadd2(a0[2], __builtin_bit_cast(__half2, vv[k].z));
                a0[3] = __hadd2(a0[3], __builtin_bit_cast(__half2, vv[k].w));
            }
        }
    }
    // a1: full-wave reduce (strides 1..32); a0: group reduce (strides 4..32)
    #pragma unroll
    for (int d = 1; d <= 32; d <<= 1) {
        #pragma unroll
        for (int r = 0; r < 4; r++) {
            unsigned int u = __shfl_xor(__builtin_bit_cast(unsigned int, a1[r]), d);
            a1[r] = __hadd2(a1[r], __builtin_bit_cast(__half2, u));
            if (d >= 4) {
                unsigned int u0 = __shfl_xor(__builtin_bit_cast(unsigned int, a0[r]), d);
                a0[r] = __hadd2(a0[r], __builtin_bit_cast(__half2, u0));
            }
        }
    }
    float val0[8], val1[8];
    if (g == 0) {   // lanes 0..3: classes [fl*8, fl*8+8)
        float acc[8];
        #pragma unroll
        for (int r = 0; r < 4; r++) {
            float2 f = __half22float2(a0[r]);
            acc[2 * r] = f.x; acc[2 * r + 1] = f.y;
        }
        uint4 s4 = pA[(size_t)i * 4 + fl];          // self (pre-scaled)
        acc8f(acc, s4, 1.0f);
        float4 bb0 = *(const float4*)(b2 + fl * 8);
        float4 bb1 = *(const float4*)(b2 + fl * 8 + 4);
        val0[0] = fmaf(acc[0], di, bb0.x);
        val0[1] = fmaf(acc[1], di, bb0.y);
        val0[2] = fmaf(acc[2], di, bb0.z);
        val0[3] = fmaf(acc[3], di, bb0.w);
        val0[4] = fmaf(acc[4], di, bb1.x);
        val0[5] = fmaf(acc[5], di, bb1.y);
        val0[6] = fmaf(acc[6], di, bb1.z);
        val0[7] = fmaf(acc[7], di, bb1.w);
    }
    if (lane == 0) {  // classes 32..39
        float acc[8];
        #pragma unroll
        for (int r = 0; r < 4; r++) {
            float2 f = __half22float2(a1[r]);
            acc[2 * r] = f.x; acc[2 * r + 1] = f.y;
        }
        acc8f(acc, pB[i], 1.0f);                    // self (pre-scaled)
        float4 bb0 = *(const float4*)(b2 + 32);
        float4 bb1 = *(const float4*)(b2 + 36);
        val1[0] = fmaf(acc[0], di, bb0.x);
        val1[1] = fmaf(acc[1], di, bb0.y);
        val1[2] = fmaf(acc[2], di, bb0.z);
        val1[3] = fmaf(acc[3], di, bb0.w);
        val1[4] = fmaf(acc[4], di, bb1.x);
        val1[5] = fmaf(acc[5], di, bb1.y);
        val1[6] = fmaf(acc[6], di, bb1.z);
        val1[7] = fmaf(acc[7], di, bb1.w);
    }
    // softmax over 40 classes: lanes 0..3 hold val0, lane 0 additionally val1
    float m = -INFINITY;
    if (g == 0) {
        #pragma unroll
        for (int k = 0; k < 8; k++) m = fmaxf(m, val0[k]);
    }
    if (lane == 0) {
        #pragma unroll
        for (int k = 0; k < 8; k++) m = fmaxf(m, val1[k]);
    }
    m = fmaxf(m, __shfl_xor(m, 1));
    m = fmaxf(m, __shfl_xor(m, 2));
    float ssum = 0.f;
    if (g == 0) {
        #pragma unroll
        for (int k = 0; k < 8; k++) ssum += expf(val0[k] - m);
    }
    if (lane == 0) {
        #pragma unroll
        for (int k = 0; k < 8; k++) ssum += expf(val1[k] - m);
    }
    ssum += __shfl_xor(ssum, 1);
    ssum += __shfl_xor(ssum, 2);
    if (g == 0) {
        float ls = m + logf(ssum);
        float4 r0 = make_float4(val0[0] - ls, val0[1] - ls, val0[2] - ls, val0[3] - ls);
        float4 r1 = make_float4(val0[4] - ls, val0[5] - ls, val0[6] - ls, val0[7] - ls);
        float4* orow = (float4*)(out + (size_t)i * NCLASS + fl * 8);
        orow[0] = r0;
        orow[1] = r1;
        if (lane == 0) {
            float4 r2 = make_float4(val1[0] - ls, val1[1] - ls, val1[2] - ls, val1[3] - ls);
            float4 r3 = make_float4(val1[4] - ls, val1[5] - ls, val1[6] - ls, val1[7] - ls);
            float4* orow1 = (float4*)(out + (size_t)i * NCLASS + 32);
            orow1[0] = r2;
            orow1[1] = r3;
        }
    }
}

extern "C" void kernel_launch(void* const* d_in, const int* in_sizes, int n_in,
                              void* d_out, int out_size, void* d_ws, size_t ws_size,
                              hipStream_t stream) {
    const float* x    = (const float*)d_in[0];
    const int*   ei   = (const int*)d_in[1];
    const float* W1   = (const float*)d_in[2];
    const float* b1   = (const float*)d_in[3];
    const float* W2   = (const float*)d_in[4];
    const float* b2   = (const float*)d_in[5];
    const float* mask = (const float*)d_in[6];
    float* out = (float*)d_out;

    const int* src = ei;
    const int* dst = ei + N_EDGES;

    char* ws = (char*)d_ws;
    size_t off = 0;
    __half* h1p    = (__half*)(ws + off); off += (size_t)NPAD * NHID * 2;      // 12.8 MB
    __half* h1h    = (__half*)(ws + off); off += (size_t)NPAD * NHID * 2;      // 12.8 MB
    int*    esrc   = (int*)   (ws + off); off += (size_t)NBUCK * CAP * 4 + 256;// 8.0 MB
    int*    deg    = (int*)   (ws + off); off += (size_t)NPAD * 4;
    float*  dinv   = (float*) (ws + off); off += (size_t)NPAD * 4;
    int*   row_beg = (int*)   (ws + off); off += (size_t)NPAD * 4;
    int*   row_cnt = (int*)   (ws + off); off += (size_t)NPAD * 4;
    int*    gcur   = (int*)   (ws + off); off += 2048;
    __half* w1t    = (__half*)(ws + off); off += 128 * 256 * 2;                // 64 KB
    __half* w2t    = (__half*)(ws + off); off += 48 * 128 * 2;                 // 12 KB

    unsigned int* packed = (unsigned int*)h1p;  // binA/fused-binB lifetime only
    __half* h2pl = h1h;                          // gemm2/agg2 lifetime (4.0 MB used)

    k_prep<<<196, 256, 0, stream>>>(W1, W2, w1t, w2t, gcur, deg);
    k_binA<<<(N_EDGES + EPB - 1) / EPB, 256, 0, stream>>>(src, dst, gcur, deg, packed);
    k_dinv<<<196, 256, 0, stream>>>(deg, dinv);
    k_fused<<<FUSE_BLOCKS, 256, 0, stream>>>(gcur, packed, esrc, row_beg, row_cnt,
                                             x, w1t, dinv, h1h);
    k_agg1<<<N_NODES, 64, 0, stream>>>(h1h, dinv, row_beg, row_cnt, esrc, b1, mask, h1p);
    k_gemm2<<<NPAD / 64, 256, 0, stream>>>(h1p, w2t, dinv, h2pl);
    k_agg2<<<N_NODES, 64, 0, stream>>>(h2pl, dinv, row_beg, row_cnt, esrc, b2, out);
}

// Round 8
// 275.366 us; speedup vs baseline: 7.2905x; 1.1853x over previous
//
#include <hip/hip_runtime.h>
#include <hip/hip_fp16.h>
#include <math.h>

#define N_NODES 50000
#define N_EDGES 1600000
#define NFEAT 256
#define NHID 128
#define NCLASS 40

#define NPAD 50048           // grid-rounded node count (dummy zero rows >= N_NODES)
#define DUMMY N_NODES        // index of a guaranteed-zero table row

#define BSHIFT 7
#define NBUCK 391            // ceil(50000 / 128)
#define CAP 5120             // per-bucket capacity (mean 4092)
#define EPB 4096             // edges per binA block -> 391 blocks

typedef _Float16 f16x8 __attribute__((ext_vector_type(8)));
typedef float f32x4 __attribute__((ext_vector_type(4)));

// ---------------- prep: W transposes to fp16 + zero gcur + zero dinv tail ----------------
__global__ __launch_bounds__(256) void k_prep(const float* __restrict__ W1,
                                              const float* __restrict__ W2,
                                              __half* __restrict__ w1t,
                                              __half* __restrict__ w2t,
                                              int* __restrict__ gcur,
                                              float* __restrict__ dinv) {
    int t = blockIdx.x * 256 + threadIdx.x;
    if (t < NBUCK) gcur[t] = 0;
    if (t >= N_NODES && t < NPAD) dinv[t] = 0.0f;   // guard: dummy-row scale factors
    if (t < 128 * 256) {
        int n = t >> 8, k = t & 255;
        w1t[t] = __float2half(W1[k * NHID + n]);
    }
    if (t < 48 * 128) {
        int n = t >> 7, k = t & 127;
        w2t[t] = __float2half(n < NCLASS ? W2[k * NCLASS + n] : 0.0f);
    }
}

// ---------------- FUSED: blocks [0,NBUCK) = binA; blocks [NBUCK, NBUCK+782) = GEMM1 (unscaled) ----------------
#define G1_LDA 72
#define G1_LDB 72
#define G1_LDE 136
#define FUSE_BLOCKS (NBUCK + NPAD / 64)
__global__ __launch_bounds__(256) void k_fuseA(const int* __restrict__ src,
                                               const int* __restrict__ dst,
                                               int* __restrict__ gcur,
                                               unsigned int* __restrict__ packed,
                                               const float* __restrict__ x,
                                               const __half* __restrict__ w1t,
                                               __half* __restrict__ h1h) {
    __shared__ __align__(16) char smem[27648];
    int t = threadIdx.x;
    if (blockIdx.x < NBUCK) {
        // ---- binA: coarse binning by dst>>7 (local hist -> global reserve -> scatter) ----
        int* lhist = (int*)smem;
        int* lbase = (int*)(smem + 4 * NBUCK);
        int* lcur  = (int*)(smem + 8 * NBUCK);
        for (int i = t; i < NBUCK; i += 256) { lhist[i] = 0; lcur[i] = 0; }
        __syncthreads();
        int e0 = blockIdx.x * EPB;
        int e1 = min(e0 + EPB, N_EDGES);
        for (int e = e0 + t; e < e1; e += 256) {
            int b = dst[e] >> BSHIFT;
            atomicAdd(&lhist[b], 1);
        }
        __syncthreads();
        for (int i = t; i < NBUCK; i += 256)
            lbase[i] = atomicAdd(&gcur[i], lhist[i]);
        __syncthreads();
        for (int e = e0 + t; e < e1; e += 256) {
            int d = dst[e];
            int b = d >> BSHIFT;
            int r = atomicAdd(&lcur[b], 1);
            int pos = lbase[b] + r;
            if (pos < CAP)
                packed[(size_t)b * CAP + pos] =
                    ((unsigned int)src[e] << BSHIFT) | (unsigned int)(d & 127);
        }
    } else {
        // ---- GEMM1: h1h(fp16, UNSCALED) = x @ W1 ----
        __half* sA = (__half*)smem;                      // 64*72*2 = 9216 B
        __half* sB = (__half*)smem + 64 * G1_LDA;        // 128*72*2 = 18432 B
        int rbase = (blockIdx.x - NBUCK) * 64;
        int lane = t & 63, wv = t >> 6;
        int m = lane & 15, quad = lane >> 4;
        f32x4 acc[8];
        #pragma unroll
        for (int i = 0; i < 8; i++) acc[i] = (f32x4)0.0f;

        int arow = t >> 2, aseg = t & 3;
        int grow = rbase + arow;
        bool avalid = grow < N_NODES;
        int bn = t >> 1, bseg = t & 1;

        for (int k0 = 0; k0 < NFEAT; k0 += 64) {
            const float4* gs = (const float4*)(x + (size_t)grow * NFEAT + k0 + aseg * 16);
            __half* ad = sA + arow * G1_LDA + aseg * 16;
            #pragma unroll
            for (int i = 0; i < 4; i++) {
                float4 v = avalid ? gs[i] : make_float4(0.f, 0.f, 0.f, 0.f);
                __half2 h0 = __float22half2_rn(make_float2(v.x, v.y));
                __half2 h1 = __float22half2_rn(make_float2(v.z, v.w));
                uint2 st;
                st.x = __builtin_bit_cast(unsigned int, h0);
                st.y = __builtin_bit_cast(unsigned int, h1);
                *(uint2*)(ad + i * 4) = st;
            }
            const uint4* ws4 = (const uint4*)(w1t + bn * NFEAT + k0 + bseg * 32);
            uint4* bd = (uint4*)(sB + bn * G1_LDB + bseg * 32);
            #pragma unroll
            for (int i = 0; i < 4; i++) bd[i] = ws4[i];
            __syncthreads();
            #pragma unroll
            for (int kk = 0; kk < 64; kk += 32) {
                f16x8 af = *(const f16x8*)(sA + (wv * 16 + m) * G1_LDA + kk + quad * 8);
                #pragma unroll
                for (int t8 = 0; t8 < 8; t8++) {
                    f16x8 bf = *(const f16x8*)(sB + (t8 * 16 + m) * G1_LDB + kk + quad * 8);
                    acc[t8] = __builtin_amdgcn_mfma_f32_16x16x32_f16(af, bf, acc[t8], 0, 0, 0);
                }
            }
            __syncthreads();
        }
        __half* eb = (__half*)smem;
        #pragma unroll
        for (int t8 = 0; t8 < 8; t8++) {
            #pragma unroll
            for (int r = 0; r < 4; r++)
                eb[(wv * 16 + quad * 4 + r) * G1_LDE + t8 * 16 + m] = __float2half(acc[t8][r]);
        }
        __syncthreads();
        {   // unconditional store: dummy rows get zeros (avalid=false staged zeros)
            const uint4* es = (const uint4*)(eb + arow * G1_LDE + aseg * 32);
            uint4* od = (uint4*)(h1h + (size_t)grow * NHID + aseg * 32);
            #pragma unroll
            for (int i = 0; i < 4; i++) od[i] = es[i];
        }
    }
}

// ---------------- binB: fine sort + CSR + dinv + in-place scale of h1h rows ----------------
__global__ __launch_bounds__(256) void k_binB(const int* __restrict__ gcur,
                                              const unsigned int* __restrict__ packed,
                                              int* __restrict__ esrc,
                                              int* __restrict__ row_beg,
                                              int* __restrict__ row_cnt,
                                              float* __restrict__ dinv,
                                              __half* __restrict__ h1h) {
    __shared__ unsigned int sp[CAP];     // 20 KB
    __shared__ int hist[128];
    __shared__ int scan[128];
    __shared__ int cur[128];
    __shared__ float sdinv[128];
    int b = blockIdx.x;
    int t = threadIdx.x;
    int cnt = min(gcur[b], CAP);
    if (t < 128) { hist[t] = 0; cur[t] = 0; }
    __syncthreads();
    const unsigned int* pin = packed + (size_t)b * CAP;
    for (int i = t; i < cnt; i += 256) {
        unsigned int w = pin[i];
        sp[i] = w;
        atomicAdd(&hist[w & 127], 1);
    }
    __syncthreads();
    if (t == 0) {
        int s = 0;
        for (int i = 0; i < 128; i++) { scan[i] = s; s += hist[i]; }
    }
    __syncthreads();
    for (int i = t; i < cnt; i += 256) {
        unsigned int w = sp[i];
        int dl = (int)(w & 127u);
        int r = atomicAdd(&cur[dl], 1);
        esrc[(size_t)b * CAP + scan[dl] + r] = (int)(w >> BSHIFT);
    }
    if (t < 128) {
        int node = b * 128 + t;
        float dv = 0.0f;
        if (node < N_NODES) {
            row_beg[node] = b * CAP + scan[t];
            row_cnt[node] = hist[t];
            dv = rsqrtf((float)(hist[t] + 1));
            dinv[node] = dv;
        }
        sdinv[t] = dv;
    }
    __syncthreads();
    // scale this bucket's 128 h1h rows (16 uint4 chunks each) by sdinv[row]
    uint4* hv = (uint4*)h1h;
    for (int idx = t; idx < 128 * 16; idx += 256) {
        int row = idx >> 4, chunk = idx & 15;
        int node = b * 128 + row;
        if (node < N_NODES) {
            float dv = sdinv[row];
            uint4 v = hv[(size_t)node * 16 + chunk];
            __half2 d2 = __half2half2(__float2half(dv));
            __half2 p0 = __hmul2(__builtin_bit_cast(__half2, v.x), d2);
            __half2 p1 = __hmul2(__builtin_bit_cast(__half2, v.y), d2);
            __half2 p2 = __hmul2(__builtin_bit_cast(__half2, v.z), d2);
            __half2 p3 = __hmul2(__builtin_bit_cast(__half2, v.w), d2);
            uint4 o;
            o.x = __builtin_bit_cast(unsigned int, p0);
            o.y = __builtin_bit_cast(unsigned int, p1);
            o.z = __builtin_bit_cast(unsigned int, p2);
            o.w = __builtin_bit_cast(unsigned int, p3);
            hv[(size_t)node * 16 + chunk] = o;
        }
    }
}

// ---------------- GEMM2 (MFMA): h2 planes = (h1p @ W2) * dinv[row] ----------------
// planeA: cls 0..31 as 64B rows (3.2MB); planeB: cls 32..39 as 16B rows (0.8MB)
#define G2_LDA 136
#define G2_LDB 136
#define G2_LDE 72
__global__ __launch_bounds__(256) void k_gemm2(const __half* __restrict__ h1p,
                                               const __half* __restrict__ w2t,
                                               const float* __restrict__ dinv,
                                               __half* __restrict__ h2pl) {
    __shared__ __half smem[64 * G2_LDA + 48 * G2_LDB];  // 30.5 KB
    __half* sA = smem;
    __half* sB = smem + 64 * G2_LDA;
    int t = threadIdx.x;
    int rbase = blockIdx.x * 64;
    int lane = t & 63, wv = t >> 6;
    int m = lane & 15, quad = lane >> 4;
    f32x4 acc[3];
    #pragma unroll
    for (int i = 0; i < 3; i++) acc[i] = (f32x4)0.0f;

    int arow = t >> 2, aseg = t & 3;
    int grow = rbase + arow;
    bool avalid = grow < N_NODES;

    #pragma unroll
    for (int i = 0; i < 3; i++) {
        int idx = t + i * 256;
        int n = idx >> 4, seg = idx & 15;
        *(uint4*)(sB + n * G2_LDB + seg * 8) = *(const uint4*)(w2t + n * NHID + seg * 8);
    }
    {
        const uint4* gs = (const uint4*)(h1p + (size_t)grow * NHID + aseg * 32);
        uint4* ad = (uint4*)(sA + arow * G2_LDA + aseg * 32);
        uint4 z; z.x = z.y = z.z = z.w = 0;
        #pragma unroll
        for (int i = 0; i < 4; i++) ad[i] = avalid ? gs[i] : z;
    }
    __syncthreads();
    #pragma unroll
    for (int kk = 0; kk < 128; kk += 32) {
        f16x8 af = *(const f16x8*)(sA + (wv * 16 + m) * G2_LDA + kk + quad * 8);
        #pragma unroll
        for (int t3 = 0; t3 < 3; t3++) {
            f16x8 bf = *(const f16x8*)(sB + (t3 * 16 + m) * G2_LDB + kk + quad * 8);
            acc[t3] = __builtin_amdgcn_mfma_f32_16x16x32_f16(af, bf, acc[t3], 0, 0, 0);
        }
    }
    __syncthreads();
    float di4[4];
    #pragma unroll
    for (int r = 0; r < 4; r++) di4[r] = dinv[rbase + wv * 16 + quad * 4 + r];
    __half* eb = smem;
    #pragma unroll
    for (int t3 = 0; t3 < 3; t3++) {
        #pragma unroll
        for (int r = 0; r < 4; r++)
            eb[(wv * 16 + quad * 4 + r) * G2_LDE + t3 * 16 + m] = __float2half(acc[t3][r] * di4[r]);
    }
    __syncthreads();
    __half* pA = h2pl;
    __half* pB = h2pl + (size_t)NPAD * 32;
    #pragma unroll
    for (int i = 0; i < 2; i++) {
        int idx = t + i * 256;
        int row = idx >> 3, seg = idx & 7;
        int gr = rbase + row;   // unconditional: dummy rows store zeros (acc=0)
        if (seg <= 4) {
            uint4 v = *(const uint4*)(eb + row * G2_LDE + seg * 8);
            if (seg < 4) ((uint4*)pA)[(size_t)gr * 4 + seg] = v;
            else        ((uint4*)pB)[gr] = v;
        }
    }
}

__device__ __forceinline__ void acc8f(float* acc, uint4 v, float d) {
    float2 a0 = __half22float2(__builtin_bit_cast(__half2, v.x));
    float2 a1 = __half22float2(__builtin_bit_cast(__half2, v.y));
    float2 a2 = __half22float2(__builtin_bit_cast(__half2, v.z));
    float2 a3 = __half22float2(__builtin_bit_cast(__half2, v.w));
    acc[0] = fmaf(a0.x, d, acc[0]); acc[1] = fmaf(a0.y, d, acc[1]);
    acc[2] = fmaf(a1.x, d, acc[2]); acc[3] = fmaf(a1.y, d, acc[3]);
    acc[4] = fmaf(a2.x, d, acc[4]); acc[5] = fmaf(a2.y, d, acc[5]);
    acc[6] = fmaf(a3.x, d, acc[6]); acc[7] = fmaf(a3.y, d, acc[7]);
}

// ---------------- agg1: round-5 structure (UNCHANGED, 53 us control) ----------------
__global__ __launch_bounds__(64) void k_agg1(const __half* __restrict__ h1h,
                                             const float* __restrict__ dinv,
                                             const int* __restrict__ row_beg,
                                             const int* __restrict__ row_cnt,
                                             const int* __restrict__ esrc,
                                             const float* __restrict__ b1,
                                             const float* __restrict__ mask,
                                             __half* __restrict__ h1p) {
    int i = blockIdx.x;
    int lane = threadIdx.x;
    int q = lane >> 4;
    int fl = lane & 15;
    const uint4* hv4 = (const uint4*)h1h;
    float di = dinv[i];
    __half2 hacc[4];
    __half2 hz = __half2half2(__float2half(0.0f));
    hacc[0] = hz; hacc[1] = hz; hacc[2] = hz; hacc[3] = hz;
    int s0 = row_beg[i], cnt = row_cnt[i];
    for (int base = 0; base < cnt; base += 64) {
        int idx = base + lane;
        int sv = (idx < cnt) ? esrc[s0 + idx] : DUMMY;   // dummy row = zeros
        int n = min(64, cnt - base);
        int nr = (n + 31) & ~31;
        for (int j = 0; j < nr; j += 32) {
            int ss[8]; uint4 vv[8];
            #pragma unroll
            for (int k = 0; k < 8; k++) ss[k] = __shfl(sv, j + 4 * k + q);
            #pragma unroll
            for (int k = 0; k < 8; k++) vv[k] = hv4[(size_t)ss[k] * 16 + fl];
            #pragma unroll
            for (int k = 0; k < 8; k++) {
                hacc[0] = __hadd2(hacc[0], __builtin_bit_cast(__half2, vv[k].x));
                hacc[1] = __hadd2(hacc[1], __builtin_bit_cast(__half2, vv[k].y));
                hacc[2] = __hadd2(hacc[2], __builtin_bit_cast(__half2, vv[k].z));
                hacc[3] = __hadd2(hacc[3], __builtin_bit_cast(__half2, vv[k].w));
            }
        }
    }
    #pragma unroll
    for (int d = 16; d <= 32; d <<= 1) {
        #pragma unroll
        for (int r = 0; r < 4; r++) {
            unsigned int u = __shfl_xor(__builtin_bit_cast(unsigned int, hacc[r]), d);
            hacc[r] = __hadd2(hacc[r], __builtin_bit_cast(__half2, u));
        }
    }
    if (q == 0) {
        float acc[8];
        #pragma unroll
        for (int r = 0; r < 4; r++) {
            float2 f = __half22float2(hacc[r]);
            acc[2 * r] = f.x; acc[2 * r + 1] = f.y;
        }
        uint4 sv4 = hv4[(size_t)i * 16 + fl];      // self row (already *dinv[i])
        acc8f(acc, sv4, 1.0f);
        float4 bb0 = ((const float4*)b1)[fl * 2];
        float4 bb1 = ((const float4*)b1)[fl * 2 + 1];
        const float4* mrow = (const float4*)(mask + (size_t)i * NHID);
        float4 mm0 = mrow[fl * 2];
        float4 mm1 = mrow[fl * 2 + 1];
        float o0 = fmaxf(fmaf(acc[0], di, bb0.x), 0.f) * mm0.x;
        float o1 = fmaxf(fmaf(acc[1], di, bb0.y), 0.f) * mm0.y;
        float o2 = fmaxf(fmaf(acc[2], di, bb0.z), 0.f) * mm0.z;
        float o3 = fmaxf(fmaf(acc[3], di, bb0.w), 0.f) * mm0.w;
        float o4 = fmaxf(fmaf(acc[4], di, bb1.x), 0.f) * mm1.x;
        float o5 = fmaxf(fmaf(acc[5], di, bb1.y), 0.f) * mm1.y;
        float o6 = fmaxf(fmaf(acc[6], di, bb1.z), 0.f) * mm1.z;
        float o7 = fmaxf(fmaf(acc[7], di, bb1.w), 0.f) * mm1.w;
        __half2 p0 = __float22half2_rn(make_float2(o0, o1));
        __half2 p1 = __float22half2_rn(make_float2(o2, o3));
        __half2 p2 = __float22half2_rn(make_float2(o4, o5));
        __half2 p3 = __float22half2_rn(make_float2(o6, o7));
        uint4 st;
        st.x = __builtin_bit_cast(unsigned int, p0);
        st.y = __builtin_bit_cast(unsigned int, p1);
        st.z = __builtin_bit_cast(unsigned int, p2);
        st.w = __builtin_bit_cast(unsigned int, p3);
        ((uint4*)h1p)[(size_t)i * 16 + fl] = st;
    }
}

// ---------------- agg2: slim planes (64B + 16B rows), wave-per-node, + log_softmax ----------------
__global__ __launch_bounds__(64) void k_agg2(const __half* __restrict__ h2pl,
                                             const float* __restrict__ dinv,
                                             const int* __restrict__ row_beg,
                                             const int* __restrict__ row_cnt,
                                             const int* __restrict__ esrc,
                                             const float* __restrict__ b2,
                                             float* __restrict__ out) {
    int i = blockIdx.x;
    int lane = threadIdx.x;
    int g = lane >> 2;        // 16 edge groups
    int fl = lane & 3;        // 16B chunk of 64B planeA row
    const uint4* pA = (const uint4*)h2pl;
    const uint4* pB = (const uint4*)(h2pl + (size_t)NPAD * 32);
    float di = dinv[i];
    __half2 a0[4], a1[4];
    __half2 hz = __half2half2(__float2half(0.0f));
    #pragma unroll
    for (int r = 0; r < 4; r++) { a0[r] = hz; a1[r] = hz; }
    int s0 = row_beg[i], cnt = row_cnt[i];
    for (int base = 0; base < cnt; base += 64) {
        int idx = base + lane;
        int sv = (idx < cnt) ? esrc[s0 + idx] : DUMMY;
        // planeB: one edge per lane (16B row, zeros at DUMMY)
        uint4 v1 = pB[sv];
        a1[0] = __hadd2(a1[0], __builtin_bit_cast(__half2, v1.x));
        a1[1] = __hadd2(a1[1], __builtin_bit_cast(__half2, v1.y));
        a1[2] = __hadd2(a1[2], __builtin_bit_cast(__half2, v1.z));
        a1[3] = __hadd2(a1[3], __builtin_bit_cast(__half2, v1.w));
        // planeA: 16 groups x depth 2 => 32 edges per j-step
        int n = min(64, cnt - base);
        int nr = (n + 31) & ~31;
        for (int j = 0; j < nr; j += 32) {
            int ss[2]; uint4 vv[2];
            #pragma unroll
            for (int k = 0; k < 2; k++) ss[k] = __shfl(sv, j + 16 * k + g);
            #pragma unroll
            for (int k = 0; k < 2; k++) vv[k] = pA[(size_t)ss[k] * 4 + fl];
            #pragma unroll
            for (int k = 0; k < 2; k++) {
                a0[0] = __hadd2(a0[0], __builtin_bit_cast(__half2, vv[k].x));
                a0[1] = __hadd2(a0[1], __builtin_bit_cast(__half2, vv[k].y));
                a0[2] = __hadd2(a0[2], __builtin_bit_cast(__half2, vv[k].z));
                a0[3] = __hadd2(a0[3], __builtin_bit_cast(__half2, vv[k].w));
            }
        }
    }
    // a1: full-wave reduce (strides 1..32); a0: group reduce (strides 4..32)
    #pragma unroll
    for (int d = 1; d <= 32; d <<= 1) {
        #pragma unroll
        for (int r = 0; r < 4; r++) {
            unsigned int u = __shfl_xor(__builtin_bit_cast(unsigned int, a1[r]), d);
            a1[r] = __hadd2(a1[r], __builtin_bit_cast(__half2, u));
            if (d >= 4) {
                unsigned int u0 = __shfl_xor(__builtin_bit_cast(unsigned int, a0[r]), d);
                a0[r] = __hadd2(a0[r], __builtin_bit_cast(__half2, u0));
            }
        }
    }
    float val0[8], val1[8];
    if (g == 0) {   // lanes 0..3: classes [fl*8, fl*8+8)
        float acc[8];
        #pragma unroll
        for (int r = 0; r < 4; r++) {
            float2 f = __half22float2(a0[r]);
            acc[2 * r] = f.x; acc[2 * r + 1] = f.y;
        }
        uint4 s4 = pA[(size_t)i * 4 + fl];          // self (pre-scaled)
        acc8f(acc, s4, 1.0f);
        float4 bb0 = *(const float4*)(b2 + fl * 8);
        float4 bb1 = *(const float4*)(b2 + fl * 8 + 4);
        val0[0] = fmaf(acc[0], di, bb0.x);
        val0[1] = fmaf(acc[1], di, bb0.y);
        val0[2] = fmaf(acc[2], di, bb0.z);
        val0[3] = fmaf(acc[3], di, bb0.w);
        val0[4] = fmaf(acc[4], di, bb1.x);
        val0[5] = fmaf(acc[5], di, bb1.y);
        val0[6] = fmaf(acc[6], di, bb1.z);
        val0[7] = fmaf(acc[7], di, bb1.w);
    }
    if (lane == 0) {  // classes 32..39
        float acc[8];
        #pragma unroll
        for (int r = 0; r < 4; r++) {
            float2 f = __half22float2(a1[r]);
            acc[2 * r] = f.x; acc[2 * r + 1] = f.y;
        }
        acc8f(acc, pB[i], 1.0f);                    // self (pre-scaled)
        float4 bb0 = *(const float4*)(b2 + 32);
        float4 bb1 = *(const float4*)(b2 + 36);
        val1[0] = fmaf(acc[0], di, bb0.x);
        val1[1] = fmaf(acc[1], di, bb0.y);
        val1[2] = fmaf(acc[2], di, bb0.z);
        val1[3] = fmaf(acc[3], di, bb0.w);
        val1[4] = fmaf(acc[4], di, bb1.x);
        val1[5] = fmaf(acc[5], di, bb1.y);
        val1[6] = fmaf(acc[6], di, bb1.z);
        val1[7] = fmaf(acc[7], di, bb1.w);
    }
    // softmax over 40 classes: lanes 0..3 hold val0, lane 0 additionally val1
    float m = -INFINITY;
    if (g == 0) {
        #pragma unroll
        for (int k = 0; k < 8; k++) m = fmaxf(m, val0[k]);
    }
    if (lane == 0) {
        #pragma unroll
        for (int k = 0; k < 8; k++) m = fmaxf(m, val1[k]);
    }
    m = fmaxf(m, __shfl_xor(m, 1));
    m = fmaxf(m, __shfl_xor(m, 2));
    float ssum = 0.f;
    if (g == 0) {
        #pragma unroll
        for (int k = 0; k < 8; k++) ssum += expf(val0[k] - m);
    }
    if (lane == 0) {
        #pragma unroll
        for (int k = 0; k < 8; k++) ssum += expf(val1[k] - m);
    }
    ssum += __shfl_xor(ssum, 1);
    ssum += __shfl_xor(ssum, 2);
    if (g == 0) {
        float ls = m + logf(ssum);
        float4 r0 = make_float4(val0[0] - ls, val0[1] - ls, val0[2] - ls, val0[3] - ls);
        float4 r1 = make_float4(val0[4] - ls, val0[5] - ls, val0[6] - ls, val0[7] - ls);
        float4* orow = (float4*)(out + (size_t)i * NCLASS + fl * 8);
        orow[0] = r0;
        orow[1] = r1;
        if (lane == 0) {
            float4 r2 = make_float4(val1[0] - ls, val1[1] - ls, val1[2] - ls, val1[3] - ls);
            float4 r3 = make_float4(val1[4] - ls, val1[5] - ls, val1[6] - ls, val1[7] - ls);
            float4* orow1 = (float4*)(out + (size_t)i * NCLASS + 32);
            orow1[0] = r2;
            orow1[1] = r3;
        }
    }
}

extern "C" void kernel_launch(void* const* d_in, const int* in_sizes, int n_in,
                              void* d_out, int out_size, void* d_ws, size_t ws_size,
                              hipStream_t stream) {
    const float* x    = (const float*)d_in[0];
    const int*   ei   = (const int*)d_in[1];
    const float* W1   = (const float*)d_in[2];
    const float* b1   = (const float*)d_in[3];
    const float* W2   = (const float*)d_in[4];
    const float* b2   = (const float*)d_in[5];
    const float* mask = (const float*)d_in[6];
    float* out = (float*)d_out;

    const int* src = ei;
    const int* dst = ei + N_EDGES;

    char* ws = (char*)d_ws;
    size_t off = 0;
    __half* h1p    = (__half*)(ws + off); off += (size_t)NPAD * NHID * 2;      // 12.8 MB
    __half* h1h    = (__half*)(ws + off); off += (size_t)NPAD * NHID * 2;      // 12.8 MB
    int*    esrc   = (int*)   (ws + off); off += (size_t)NBUCK * CAP * 4 + 256;// 8.0 MB
    float*  dinv   = (float*) (ws + off); off += (size_t)NPAD * 4;
    int*   row_beg = (int*)   (ws + off); off += (size_t)NPAD * 4;
    int*   row_cnt = (int*)   (ws + off); off += (size_t)NPAD * 4;
    int*    gcur   = (int*)   (ws + off); off += 2048;
    __half* w1t    = (__half*)(ws + off); off += 128 * 256 * 2;                // 64 KB
    __half* w2t    = (__half*)(ws + off); off += 48 * 128 * 2;                 // 12 KB

    unsigned int* packed = (unsigned int*)h1p;  // binA lifetime only (h1p written later by agg1)
    __half* h2pl = h1h;                          // gemm2/agg2 lifetime (4.0 MB used)

    k_prep<<<196, 256, 0, stream>>>(W1, W2, w1t, w2t, gcur, dinv);
    k_fuseA<<<FUSE_BLOCKS, 256, 0, stream>>>(src, dst, gcur, packed, x, w1t, h1h);
    k_binB<<<NBUCK, 256, 0, stream>>>(gcur, packed, esrc, row_beg, row_cnt, dinv, h1h);
    k_agg1<<<N_NODES, 64, 0, stream>>>(h1h, dinv, row_beg, row_cnt, esrc, b1, mask, h1p);
    k_gemm2<<<NPAD / 64, 256, 0, stream>>>(h1p, w2t, dinv, h2pl);
    k_agg2<<<N_NODES, 64, 0, stream>>>(h2pl, dinv, row_beg, row_cnt, esrc, b2, out);
}

// Round 10
// 269.913 us; speedup vs baseline: 7.4378x; 1.0202x over previous
//
#include <hip/hip_runtime.h>
#include <hip/hip_fp16.h>
#include <math.h>

#define N_NODES 50000
#define N_EDGES 1600000
#define NFEAT 256
#define NHID 128
#define NCLASS 40

#define NPAD 50048           // grid-rounded node count (dummy zero rows >= N_NODES)
#define DUMMY N_NODES        // index of a guaranteed-zero table row

#define BSHIFT 7
#define NBUCK 391            // ceil(50000 / 128)
#define CAP 5120             // per-bucket capacity (mean 4092)
#define EPB 4096             // edges per binA block -> 391 blocks

typedef _Float16 f16x8 __attribute__((ext_vector_type(8)));
typedef float f32x4 __attribute__((ext_vector_type(4)));
typedef float fv4 __attribute__((ext_vector_type(4)));      // nt-capable float4
typedef unsigned int uv4 __attribute__((ext_vector_type(4))); // nt-capable uint4

// ---------------- pass A: coarse binning by dst>>7 ----------------
__global__ __launch_bounds__(256) void k_binA(const int* __restrict__ src,
                                              const int* __restrict__ dst,
                                              int* __restrict__ gcur,
                                              unsigned int* __restrict__ packed) {
    __shared__ int lhist[NBUCK];
    __shared__ int lbase[NBUCK];
    __shared__ int lcur[NBUCK];
    int t = threadIdx.x;
    for (int i = t; i < NBUCK; i += 256) { lhist[i] = 0; lcur[i] = 0; }
    __syncthreads();
    int e0 = blockIdx.x * EPB;
    int e1 = min(e0 + EPB, N_EDGES);
    for (int e = e0 + t; e < e1; e += 256) {
        int b = dst[e] >> BSHIFT;
        atomicAdd(&lhist[b], 1);
    }
    __syncthreads();
    for (int i = t; i < NBUCK; i += 256)
        lbase[i] = atomicAdd(&gcur[i], lhist[i]);
    __syncthreads();
    for (int e = e0 + t; e < e1; e += 256) {
        int d = dst[e];
        int b = d >> BSHIFT;
        int r = atomicAdd(&lcur[b], 1);
        int pos = lbase[b] + r;
        if (pos < CAP)
            packed[(size_t)b * CAP + pos] =
                ((unsigned int)src[e] << BSHIFT) | (unsigned int)(d & 127);
    }
}

// ---------------- pass B: in-LDS fine sort per bucket + CSR metadata + dinv ----------------
__global__ __launch_bounds__(256) void k_binB(const int* __restrict__ gcur,
                                              const unsigned int* __restrict__ packed,
                                              int* __restrict__ esrc,
                                              int* __restrict__ row_beg,
                                              int* __restrict__ row_cnt,
                                              float* __restrict__ dinv) {
    __shared__ unsigned int sp[CAP];     // 20 KB
    __shared__ int hist[128];
    __shared__ int scan[128];
    __shared__ int cur[128];
    int b = blockIdx.x;
    int t = threadIdx.x;
    int cnt = min(gcur[b], CAP);
    if (t < 128) { hist[t] = 0; cur[t] = 0; }
    __syncthreads();
    const unsigned int* pin = packed + (size_t)b * CAP;
    for (int i = t; i < cnt; i += 256) {
        unsigned int w = pin[i];
        sp[i] = w;
        atomicAdd(&hist[w & 127], 1);
    }
    __syncthreads();
    if (t == 0) {
        int s = 0;
        for (int i = 0; i < 128; i++) { scan[i] = s; s += hist[i]; }
    }
    __syncthreads();
    for (int i = t; i < cnt; i += 256) {
        unsigned int w = sp[i];
        int dl = (int)(w & 127u);
        int r = atomicAdd(&cur[dl], 1);
        esrc[(size_t)b * CAP + scan[dl] + r] = (int)(w >> BSHIFT);
    }
    if (t < 128) {
        int node = b * 128 + t;
        if (node < N_NODES) {
            row_beg[node] = b * CAP + scan[t];
            row_cnt[node] = hist[t];
            dinv[node] = rsqrtf((float)(hist[t] + 1));
        }
    }
}

// ---------------- prep: W transposes to fp16 + gcur zero + dinv tail zero ----------------
__global__ __launch_bounds__(256) void k_prep(const float* __restrict__ W1,
                                              const float* __restrict__ W2,
                                              __half* __restrict__ w1t,
                                              __half* __restrict__ w2t,
                                              int* __restrict__ gcur,
                                              float* __restrict__ dinv) {
    int t = blockIdx.x * 256 + threadIdx.x;
    if (t < NBUCK) gcur[t] = 0;
    if (t >= N_NODES && t < NPAD) dinv[t] = 0.0f;   // dummy rows scale to zero
    if (t < 128 * 256) {
        int n = t >> 8, k = t & 255;
        w1t[t] = __float2half(W1[k * NHID + n]);
    }
    if (t < 48 * 128) {
        int n = t >> 7, k = t & 127;
        w2t[t] = __float2half(n < NCLASS ? W2[k * NCLASS + n] : 0.0f);
    }
}

// ---------------- GEMM1 (MFMA): h1h(fp16) = (x @ W1) * dinv[row]  (pre-scaled table) ----------------
#define G1_LDA 72
#define G1_LDB 72
#define G1_LDE 136
__global__ __launch_bounds__(256) void k_gemm1(const float* __restrict__ x,
                                               const __half* __restrict__ w1t,
                                               const float* __restrict__ dinv,
                                               __half* __restrict__ h1h) {
    __shared__ __half smem[64 * G1_LDA + 128 * G1_LDB];   // 27.6 KB
    __half* sA = smem;
    __half* sB = smem + 64 * G1_LDA;
    int t = threadIdx.x;
    int rbase = blockIdx.x * 64;
    int lane = t & 63, wv = t >> 6;
    int m = lane & 15, quad = lane >> 4;
    f32x4 acc[8];
    #pragma unroll
    for (int i = 0; i < 8; i++) acc[i] = (f32x4)0.0f;

    int arow = t >> 2, aseg = t & 3;
    int grow = rbase + arow;
    bool avalid = grow < N_NODES;
    int bn = t >> 1, bseg = t & 1;

    for (int k0 = 0; k0 < NFEAT; k0 += 64) {
        const float4* gs = (const float4*)(x + (size_t)grow * NFEAT + k0 + aseg * 16);
        __half* ad = sA + arow * G1_LDA + aseg * 16;
        #pragma unroll
        for (int i = 0; i < 4; i++) {
            float4 v = avalid ? gs[i] : make_float4(0.f, 0.f, 0.f, 0.f);
            __half2 h0 = __float22half2_rn(make_float2(v.x, v.y));
            __half2 h1 = __float22half2_rn(make_float2(v.z, v.w));
            uint2 st;
            st.x = __builtin_bit_cast(unsigned int, h0);
            st.y = __builtin_bit_cast(unsigned int, h1);
            *(uint2*)(ad + i * 4) = st;
        }
        const uint4* ws4 = (const uint4*)(w1t + bn * NFEAT + k0 + bseg * 32);
        uint4* bd = (uint4*)(sB + bn * G1_LDB + bseg * 32);
        #pragma unroll
        for (int i = 0; i < 4; i++) bd[i] = ws4[i];
        __syncthreads();
        #pragma unroll
        for (int kk = 0; kk < 64; kk += 32) {
            f16x8 af = *(const f16x8*)(sA + (wv * 16 + m) * G1_LDA + kk + quad * 8);
            #pragma unroll
            for (int t8 = 0; t8 < 8; t8++) {
                f16x8 bf = *(const f16x8*)(sB + (t8 * 16 + m) * G1_LDB + kk + quad * 8);
                acc[t8] = __builtin_amdgcn_mfma_f32_16x16x32_f16(af, bf, acc[t8], 0, 0, 0);
            }
        }
        __syncthreads();
    }
    // pre-scale each output row by dinv[row] while packing (rows >= N_NODES have dinv=0 -> zero rows)
    float di4[4];
    #pragma unroll
    for (int r = 0; r < 4; r++) di4[r] = dinv[rbase + wv * 16 + quad * 4 + r];
    __half* eb = smem;
    #pragma unroll
    for (int t8 = 0; t8 < 8; t8++) {
        #pragma unroll
        for (int r = 0; r < 4; r++)
            eb[(wv * 16 + quad * 4 + r) * G1_LDE + t8 * 16 + m] = __float2half(acc[t8][r] * di4[r]);
    }
    __syncthreads();
    {   // unconditional store: grid covers exactly NPAD rows; dummy rows are zeros
        const uint4* es = (const uint4*)(eb + arow * G1_LDE + aseg * 32);
        uint4* od = (uint4*)(h1h + (size_t)grow * NHID + aseg * 32);
        #pragma unroll
        for (int i = 0; i < 4; i++) od[i] = es[i];
    }
}

// ---------------- GEMM2 (MFMA): h2 planes = (h1p @ W2) * dinv[row] ----------------
// planeA: cls 0..31 as 64B rows (3.2MB); planeB: cls 32..39 as 16B rows (0.8MB)
#define G2_LDA 136
#define G2_LDB 136
#define G2_LDE 72
__global__ __launch_bounds__(256) void k_gemm2(const __half* __restrict__ h1p,
                                               const __half* __restrict__ w2t,
                                               const float* __restrict__ dinv,
                                               __half* __restrict__ h2pl) {
    __shared__ __half smem[64 * G2_LDA + 48 * G2_LDB];  // 30.5 KB
    __half* sA = smem;
    __half* sB = smem + 64 * G2_LDA;
    int t = threadIdx.x;
    int rbase = blockIdx.x * 64;
    int lane = t & 63, wv = t >> 6;
    int m = lane & 15, quad = lane >> 4;
    f32x4 acc[3];
    #pragma unroll
    for (int i = 0; i < 3; i++) acc[i] = (f32x4)0.0f;

    int arow = t >> 2, aseg = t & 3;
    int grow = rbase + arow;
    bool avalid = grow < N_NODES;

    #pragma unroll
    for (int i = 0; i < 3; i++) {
        int idx = t + i * 256;
        int n = idx >> 4, seg = idx & 15;
        *(uint4*)(sB + n * G2_LDB + seg * 8) = *(const uint4*)(w2t + n * NHID + seg * 8);
    }
    {
        const uint4* gs = (const uint4*)(h1p + (size_t)grow * NHID + aseg * 32);
        uint4* ad = (uint4*)(sA + arow * G2_LDA + aseg * 32);
        uint4 z; z.x = z.y = z.z = z.w = 0;
        #pragma unroll
        for (int i = 0; i < 4; i++) ad[i] = avalid ? gs[i] : z;
    }
    __syncthreads();
    #pragma unroll
    for (int kk = 0; kk < 128; kk += 32) {
        f16x8 af = *(const f16x8*)(sA + (wv * 16 + m) * G2_LDA + kk + quad * 8);
        #pragma unroll
        for (int t3 = 0; t3 < 3; t3++) {
            f16x8 bf = *(const f16x8*)(sB + (t3 * 16 + m) * G2_LDB + kk + quad * 8);
            acc[t3] = __builtin_amdgcn_mfma_f32_16x16x32_f16(af, bf, acc[t3], 0, 0, 0);
        }
    }
    __syncthreads();
    float di4[4];
    #pragma unroll
    for (int r = 0; r < 4; r++) di4[r] = dinv[rbase + wv * 16 + quad * 4 + r];
    __half* eb = smem;
    #pragma unroll
    for (int t3 = 0; t3 < 3; t3++) {
        #pragma unroll
        for (int r = 0; r < 4; r++)
            eb[(wv * 16 + quad * 4 + r) * G2_LDE + t3 * 16 + m] = __float2half(acc[t3][r] * di4[r]);
    }
    __syncthreads();
    __half* pA = h2pl;
    __half* pB = h2pl + (size_t)NPAD * 32;
    #pragma unroll
    for (int i = 0; i < 2; i++) {
        int idx = t + i * 256;
        int row = idx >> 3, seg = idx & 7;
        int gr = rbase + row;   // unconditional: dummy rows store zeros (acc=0, di=0)
        if (seg <= 4) {
            uint4 v = *(const uint4*)(eb + row * G2_LDE + seg * 8);
            if (seg < 4) ((uint4*)pA)[(size_t)gr * 4 + seg] = v;
            else        ((uint4*)pB)[gr] = v;
        }
    }
}

__device__ __forceinline__ void acc8f(float* acc, uint4 v, float d) {
    float2 a0 = __half22float2(__builtin_bit_cast(__half2, v.x));
    float2 a1 = __half22float2(__builtin_bit_cast(__half2, v.y));
    float2 a2 = __half22float2(__builtin_bit_cast(__half2, v.z));
    float2 a3 = __half22float2(__builtin_bit_cast(__half2, v.w));
    acc[0] = fmaf(a0.x, d, acc[0]); acc[1] = fmaf(a0.y, d, acc[1]);
    acc[2] = fmaf(a1.x, d, acc[2]); acc[3] = fmaf(a1.y, d, acc[3]);
    acc[4] = fmaf(a2.x, d, acc[4]); acc[5] = fmaf(a2.y, d, acc[5]);
    acc[6] = fmaf(a3.x, d, acc[6]); acc[7] = fmaf(a3.y, d, acc[7]);
}

// ---------------- agg1: round-5 structure + nt hints on streaming accesses ----------------
__global__ __launch_bounds__(64) void k_agg1(const __half* __restrict__ h1h,
                                             const float* __restrict__ dinv,
                                             const int* __restrict__ row_beg,
                                             const int* __restrict__ row_cnt,
                                             const int* __restrict__ esrc,
                                             const float* __restrict__ b1,
                                             const float* __restrict__ mask,
                                             __half* __restrict__ h1p) {
    int i = blockIdx.x;
    int lane = threadIdx.x;
    int q = lane >> 4;
    int fl = lane & 15;
    const uint4* hv4 = (const uint4*)h1h;
    float di = dinv[i];
    __half2 hacc[4];
    __half2 hz = __half2half2(__float2half(0.0f));
    hacc[0] = hz; hacc[1] = hz; hacc[2] = hz; hacc[3] = hz;
    int s0 = row_beg[i], cnt = row_cnt[i];
    for (int base = 0; base < cnt; base += 64) {
        int idx = base + lane;
        int sv = (idx < cnt) ? __builtin_nontemporal_load(&esrc[s0 + idx]) : DUMMY;
        int n = min(64, cnt - base);
        int nr = (n + 31) & ~31;
        for (int j = 0; j < nr; j += 32) {
            int ss[8]; uint4 vv[8];
            #pragma unroll
            for (int k = 0; k < 8; k++) ss[k] = __shfl(sv, j + 4 * k + q);
            #pragma unroll
            for (int k = 0; k < 8; k++) vv[k] = hv4[(size_t)ss[k] * 16 + fl];
            #pragma unroll
            for (int k = 0; k < 8; k++) {
                hacc[0] = __hadd2(hacc[0], __builtin_bit_cast(__half2, vv[k].x));
                hacc[1] = __hadd2(hacc[1], __builtin_bit_cast(__half2, vv[k].y));
                hacc[2] = __hadd2(hacc[2], __builtin_bit_cast(__half2, vv[k].z));
                hacc[3] = __hadd2(hacc[3], __builtin_bit_cast(__half2, vv[k].w));
            }
        }
    }
    #pragma unroll
    for (int d = 16; d <= 32; d <<= 1) {
        #pragma unroll
        for (int r = 0; r < 4; r++) {
            unsigned int u = __shfl_xor(__builtin_bit_cast(unsigned int, hacc[r]), d);
            hacc[r] = __hadd2(hacc[r], __builtin_bit_cast(__half2, u));
        }
    }
    if (q == 0) {
        float acc[8];
        #pragma unroll
        for (int r = 0; r < 4; r++) {
            float2 f = __half22float2(hacc[r]);
            acc[2 * r] = f.x; acc[2 * r + 1] = f.y;
        }
        uint4 sv4 = hv4[(size_t)i * 16 + fl];      // self row (already *dinv[i])
        acc8f(acc, sv4, 1.0f);
        float4 bb0 = ((const float4*)b1)[fl * 2];
        float4 bb1 = ((const float4*)b1)[fl * 2 + 1];
        const fv4* mrow = (const fv4*)(mask + (size_t)i * NHID);
        fv4 mm0 = __builtin_nontemporal_load(&mrow[fl * 2]);
        fv4 mm1 = __builtin_nontemporal_load(&mrow[fl * 2 + 1]);
        float o0 = fmaxf(fmaf(acc[0], di, bb0.x), 0.f) * mm0[0];
        float o1 = fmaxf(fmaf(acc[1], di, bb0.y), 0.f) * mm0[1];
        float o2 = fmaxf(fmaf(acc[2], di, bb0.z), 0.f) * mm0[2];
        float o3 = fmaxf(fmaf(acc[3], di, bb0.w), 0.f) * mm0[3];
        float o4 = fmaxf(fmaf(acc[4], di, bb1.x), 0.f) * mm1[0];
        float o5 = fmaxf(fmaf(acc[5], di, bb1.y), 0.f) * mm1[1];
        float o6 = fmaxf(fmaf(acc[6], di, bb1.z), 0.f) * mm1[2];
        float o7 = fmaxf(fmaf(acc[7], di, bb1.w), 0.f) * mm1[3];
        __half2 p0 = __float22half2_rn(make_float2(o0, o1));
        __half2 p1 = __float22half2_rn(make_float2(o2, o3));
        __half2 p2 = __float22half2_rn(make_float2(o4, o5));
        __half2 p3 = __float22half2_rn(make_float2(o6, o7));
        uv4 st;
        st[0] = __builtin_bit_cast(unsigned int, p0);
        st[1] = __builtin_bit_cast(unsigned int, p1);
        st[2] = __builtin_bit_cast(unsigned int, p2);
        st[3] = __builtin_bit_cast(unsigned int, p3);
        __builtin_nontemporal_store(st, &((uv4*)h1p)[(size_t)i * 16 + fl]);
    }
}

// ---------------- agg2: slim planes (64B + 16B rows), wave-per-node, + log_softmax ----------------
__global__ __launch_bounds__(64) void k_agg2(const __half* __restrict__ h2pl,
                                             const float* __restrict__ dinv,
                                             const int* __restrict__ row_beg,
                                             const int* __restrict__ row_cnt,
                                             const int* __restrict__ esrc,
                                             const float* __restrict__ b2,
                                             float* __restrict__ out) {
    int i = blockIdx.x;
    int lane = threadIdx.x;
    int g = lane >> 2;        // 16 edge groups
    int fl = lane & 3;        // 16B chunk of 64B planeA row
    const uint4* pA = (const uint4*)h2pl;
    const uint4* pB = (const uint4*)(h2pl + (size_t)NPAD * 32);
    float di = dinv[i];
    __half2 a0[4], a1[4];
    __half2 hz = __half2half2(__float2half(0.0f));
    #pragma unroll
    for (int r = 0; r < 4; r++) { a0[r] = hz; a1[r] = hz; }
    int s0 = row_beg[i], cnt = row_cnt[i];
    for (int base = 0; base < cnt; base += 64) {
        int idx = base + lane;
        int sv = (idx < cnt) ? __builtin_nontemporal_load(&esrc[s0 + idx]) : DUMMY;
        // planeB: one edge per lane (16B row, zeros at DUMMY)
        uint4 v1 = pB[sv];
        a1[0] = __hadd2(a1[0], __builtin_bit_cast(__half2, v1.x));
        a1[1] = __hadd2(a1[1], __builtin_bit_cast(__half2, v1.y));
        a1[2] = __hadd2(a1[2], __builtin_bit_cast(__half2, v1.z));
        a1[3] = __hadd2(a1[3], __builtin_bit_cast(__half2, v1.w));
        // planeA: 16 groups x depth 2 => 32 edges per j-step
        int n = min(64, cnt - base);
        int nr = (n + 31) & ~31;
        for (int j = 0; j < nr; j += 32) {
            int ss[2]; uint4 vv[2];
            #pragma unroll
            for (int k = 0; k < 2; k++) ss[k] = __shfl(sv, j + 16 * k + g);
            #pragma unroll
            for (int k = 0; k < 2; k++) vv[k] = pA[(size_t)ss[k] * 4 + fl];
            #pragma unroll
            for (int k = 0; k < 2; k++) {
                a0[0] = __hadd2(a0[0], __builtin_bit_cast(__half2, vv[k].x));
                a0[1] = __hadd2(a0[1], __builtin_bit_cast(__half2, vv[k].y));
                a0[2] = __hadd2(a0[2], __builtin_bit_cast(__half2, vv[k].z));
                a0[3] = __hadd2(a0[3], __builtin_bit_cast(__half2, vv[k].w));
            }
        }
    }
    // a1: full-wave reduce (strides 1..32); a0: group reduce (strides 4..32)
    #pragma unroll
    for (int d = 1; d <= 32; d <<= 1) {
        #pragma unroll
        for (int r = 0; r < 4; r++) {
            unsigned int u = __shfl_xor(__builtin_bit_cast(unsigned int, a1[r]), d);
            a1[r] = __hadd2(a1[r], __builtin_bit_cast(__half2, u));
            if (d >= 4) {
                unsigned int u0 = __shfl_xor(__builtin_bit_cast(unsigned int, a0[r]), d);
                a0[r] = __hadd2(a0[r], __builtin_bit_cast(__half2, u0));
            }
        }
    }
    float val0[8], val1[8];
    if (g == 0) {   // lanes 0..3: classes [fl*8, fl*8+8)
        float acc[8];
        #pragma unroll
        for (int r = 0; r < 4; r++) {
            float2 f = __half22float2(a0[r]);
            acc[2 * r] = f.x; acc[2 * r + 1] = f.y;
        }
        uint4 s4 = pA[(size_t)i * 4 + fl];          // self (pre-scaled)
        acc8f(acc, s4, 1.0f);
        float4 bb0 = *(const float4*)(b2 + fl * 8);
        float4 bb1 = *(const float4*)(b2 + fl * 8 + 4);
        val0[0] = fmaf(acc[0], di, bb0.x);
        val0[1] = fmaf(acc[1], di, bb0.y);
        val0[2] = fmaf(acc[2], di, bb0.z);
        val0[3] = fmaf(acc[3], di, bb0.w);
        val0[4] = fmaf(acc[4], di, bb1.x);
        val0[5] = fmaf(acc[5], di, bb1.y);
        val0[6] = fmaf(acc[6], di, bb1.z);
        val0[7] = fmaf(acc[7], di, bb1.w);
    }
    if (lane == 0) {  // classes 32..39
        float acc[8];
        #pragma unroll
        for (int r = 0; r < 4; r++) {
            float2 f = __half22float2(a1[r]);
            acc[2 * r] = f.x; acc[2 * r + 1] = f.y;
        }
        acc8f(acc, pB[i], 1.0f);                    // self (pre-scaled)
        float4 bb0 = *(const float4*)(b2 + 32);
        float4 bb1 = *(const float4*)(b2 + 36);
        val1[0] = fmaf(acc[0], di, bb0.x);
        val1[1] = fmaf(acc[1], di, bb0.y);
        val1[2] = fmaf(acc[2], di, bb0.z);
        val1[3] = fmaf(acc[3], di, bb0.w);
        val1[4] = fmaf(acc[4], di, bb1.x);
        val1[5] = fmaf(acc[5], di, bb1.y);
        val1[6] = fmaf(acc[6], di, bb1.z);
        val1[7] = fmaf(acc[7], di, bb1.w);
    }
    // softmax over 40 classes: lanes 0..3 hold val0, lane 0 additionally val1
    float m = -INFINITY;
    if (g == 0) {
        #pragma unroll
        for (int k = 0; k < 8; k++) m = fmaxf(m, val0[k]);
    }
    if (lane == 0) {
        #pragma unroll
        for (int k = 0; k < 8; k++) m = fmaxf(m, val1[k]);
    }
    m = fmaxf(m, __shfl_xor(m, 1));
    m = fmaxf(m, __shfl_xor(m, 2));
    float ssum = 0.f;
    if (g == 0) {
        #pragma unroll
        for (int k = 0; k < 8; k++) ssum += expf(val0[k] - m);
    }
    if (lane == 0) {
        #pragma unroll
        for (int k = 0; k < 8; k++) ssum += expf(val1[k] - m);
    }
    ssum += __shfl_xor(ssum, 1);
    ssum += __shfl_xor(ssum, 2);
    if (g == 0) {
        float ls = m + logf(ssum);
        float4 r0 = make_float4(val0[0] - ls, val0[1] - ls, val0[2] - ls, val0[3] - ls);
        float4 r1 = make_float4(val0[4] - ls, val0[5] - ls, val0[6] - ls, val0[7] - ls);
        float4* orow = (float4*)(out + (size_t)i * NCLASS + fl * 8);
        orow[0] = r0;
        orow[1] = r1;
        if (lane == 0) {
            float4 r2 = make_float4(val1[0] - ls, val1[1] - ls, val1[2] - ls, val1[3] - ls);
            float4 r3 = make_float4(val1[4] - ls, val1[5] - ls, val1[6] - ls, val1[7] - ls);
            float4* orow1 = (float4*)(out + (size_t)i * NCLASS + 32);
            orow1[0] = r2;
            orow1[1] = r3;
        }
    }
}

extern "C" void kernel_launch(void* const* d_in, const int* in_sizes, int n_in,
                              void* d_out, int out_size, void* d_ws, size_t ws_size,
                              hipStream_t stream) {
    const float* x    = (const float*)d_in[0];
    const int*   ei   = (const int*)d_in[1];
    const float* W1   = (const float*)d_in[2];
    const float* b1   = (const float*)d_in[3];
    const float* W2   = (const float*)d_in[4];
    const float* b2   = (const float*)d_in[5];
    const float* mask = (const float*)d_in[6];
    float* out = (float*)d_out;

    const int* src = ei;
    const int* dst = ei + N_EDGES;

    char* ws = (char*)d_ws;
    size_t off = 0;
    __half* h1p    = (__half*)(ws + off); off += (size_t)NPAD * NHID * 2;      // 12.8 MB
    __half* h1h    = (__half*)(ws + off); off += (size_t)NPAD * NHID * 2;      // 12.8 MB
    int*    esrc   = (int*)   (ws + off); off += (size_t)NBUCK * CAP * 4 + 256;// 8.0 MB
    float*  dinv   = (float*) (ws + off); off += (size_t)NPAD * 4;
    int*   row_beg = (int*)   (ws + off); off += (size_t)NPAD * 4;
    int*   row_cnt = (int*)   (ws + off); off += (size_t)NPAD * 4;
    int*    gcur   = (int*)   (ws + off); off += 2048;
    __half* w1t    = (__half*)(ws + off); off += 128 * 256 * 2;                // 64 KB
    __half* w2t    = (__half*)(ws + off); off += 48 * 128 * 2;                 // 12 KB

    unsigned int* packed = (unsigned int*)h1p;  // binA/binB lifetime only
    __half* h2pl = h1h;                          // gemm2/agg2 lifetime (4.0 MB used)

    k_prep<<<196, 256, 0, stream>>>(W1, W2, w1t, w2t, gcur, dinv);
    k_binA<<<(N_EDGES + EPB - 1) / EPB, 256, 0, stream>>>(src, dst, gcur, packed);
    k_binB<<<NBUCK, 256, 0, stream>>>(gcur, packed, esrc, row_beg, row_cnt, dinv);

    k_gemm1<<<NPAD / 64, 256, 0, stream>>>(x, w1t, dinv, h1h);
    k_agg1<<<N_NODES, 64, 0, stream>>>(h1h, dinv, row_beg, row_cnt, esrc, b1, mask, h1p);
    k_gemm2<<<NPAD / 64, 256, 0, stream>>>(h1p, w2t, dinv, h2pl);
    k_agg2<<<N_NODES, 64, 0, stream>>>(h2pl, dinv, row_beg, row_cnt, esrc, b2, out);
}

// Round 12
// 259.535 us; speedup vs baseline: 7.7352x; 1.0400x over previous
//
#include <hip/hip_runtime.h>
#include <hip/hip_fp16.h>
#include <math.h>

#define N_NODES 50000
#define N_EDGES 1600000
#define NFEAT 256
#define NHID 128
#define NCLASS 40

#define NPAD 50048           // grid-rounded node count (dummy zero rows >= N_NODES)
#define DUMMY N_NODES        // index of a guaranteed-zero table row

#define BSHIFT 7
#define NBUCK 391            // ceil(50000 / 128)
#define CAP 5120             // per-bucket capacity (mean 4092)
#define EPB 4096             // edges per binA block -> 391 blocks

typedef _Float16 f16x8 __attribute__((ext_vector_type(8)));
typedef float f32x4 __attribute__((ext_vector_type(4)));
typedef float fv4 __attribute__((ext_vector_type(4)));      // nt-capable float4
typedef unsigned int uv4 __attribute__((ext_vector_type(4))); // nt-capable uint4

// ---------------- pass A: coarse binning by dst>>7 ----------------
__global__ __launch_bounds__(256) void k_binA(const int* __restrict__ src,
                                              const int* __restrict__ dst,
                                              int* __restrict__ gcur,
                                              unsigned int* __restrict__ packed) {
    __shared__ int lhist[NBUCK];
    __shared__ int lbase[NBUCK];
    __shared__ int lcur[NBUCK];
    int t = threadIdx.x;
    for (int i = t; i < NBUCK; i += 256) { lhist[i] = 0; lcur[i] = 0; }
    __syncthreads();
    int e0 = blockIdx.x * EPB;
    int e1 = min(e0 + EPB, N_EDGES);
    for (int e = e0 + t; e < e1; e += 256) {
        int b = dst[e] >> BSHIFT;
        atomicAdd(&lhist[b], 1);
    }
    __syncthreads();
    for (int i = t; i < NBUCK; i += 256)
        lbase[i] = atomicAdd(&gcur[i], lhist[i]);
    __syncthreads();
    for (int e = e0 + t; e < e1; e += 256) {
        int d = dst[e];
        int b = d >> BSHIFT;
        int r = atomicAdd(&lcur[b], 1);
        int pos = lbase[b] + r;
        if (pos < CAP)
            packed[(size_t)b * CAP + pos] =
                ((unsigned int)src[e] << BSHIFT) | (unsigned int)(d & 127);
    }
}

// ---------------- pass B: in-LDS fine sort per bucket + CSR metadata + dinv ----------------
__global__ __launch_bounds__(256) void k_binB(const int* __restrict__ gcur,
                                              const unsigned int* __restrict__ packed,
                                              int* __restrict__ esrc,
                                              int* __restrict__ row_beg,
                                              int* __restrict__ row_cnt,
                                              float* __restrict__ dinv) {
    __shared__ unsigned int sp[CAP];     // 20 KB
    __shared__ int hist[128];
    __shared__ int scan[128];
    __shared__ int cur[128];
    int b = blockIdx.x;
    int t = threadIdx.x;
    int cnt = min(gcur[b], CAP);
    if (t < 128) { hist[t] = 0; cur[t] = 0; }
    __syncthreads();
    const unsigned int* pin = packed + (size_t)b * CAP;
    for (int i = t; i < cnt; i += 256) {
        unsigned int w = pin[i];
        sp[i] = w;
        atomicAdd(&hist[w & 127], 1);
    }
    __syncthreads();
    if (t == 0) {
        int s = 0;
        for (int i = 0; i < 128; i++) { scan[i] = s; s += hist[i]; }
    }
    __syncthreads();
    for (int i = t; i < cnt; i += 256) {
        unsigned int w = sp[i];
        int dl = (int)(w & 127u);
        int r = atomicAdd(&cur[dl], 1);
        esrc[(size_t)b * CAP + scan[dl] + r] = (int)(w >> BSHIFT);
    }
    if (t < 128) {
        int node = b * 128 + t;
        if (node < N_NODES) {
            row_beg[node] = b * CAP + scan[t];
            row_cnt[node] = hist[t];
            dinv[node] = rsqrtf((float)(hist[t] + 1));
        }
    }
}

// ---------------- prep: W transposes to fp16 + gcur zero + dinv tail zero ----------------
__global__ __launch_bounds__(256) void k_prep(const float* __restrict__ W1,
                                              const float* __restrict__ W2,
                                              __half* __restrict__ w1t,
                                              __half* __restrict__ w2t,
                                              int* __restrict__ gcur,
                                              float* __restrict__ dinv) {
    int t = blockIdx.x * 256 + threadIdx.x;
    if (t < NBUCK) gcur[t] = 0;
    if (t >= N_NODES && t < NPAD) dinv[t] = 0.0f;   // dummy rows scale to zero
    if (t < 128 * 256) {
        int n = t >> 8, k = t & 255;
        w1t[t] = __float2half(W1[k * NHID + n]);
    }
    if (t < 48 * 128) {
        int n = t >> 7, k = t & 127;
        w2t[t] = __float2half(n < NCLASS ? W2[k * NCLASS + n] : 0.0f);
    }
}

// ---------------- GEMM1 (MFMA): h1h(fp16) = (x @ W1) * dinv[row]  (pre-scaled table) ----------------
#define G1_LDA 72
#define G1_LDB 72
#define G1_LDE 136
__global__ __launch_bounds__(256) void k_gemm1(const float* __restrict__ x,
                                               const __half* __restrict__ w1t,
                                               const float* __restrict__ dinv,
                                               __half* __restrict__ h1h) {
    __shared__ __half smem[64 * G1_LDA + 128 * G1_LDB];   // 27.6 KB
    __half* sA = smem;
    __half* sB = smem + 64 * G1_LDA;
    int t = threadIdx.x;
    int rbase = blockIdx.x * 64;
    int lane = t & 63, wv = t >> 6;
    int m = lane & 15, quad = lane >> 4;
    f32x4 acc[8];
    #pragma unroll
    for (int i = 0; i < 8; i++) acc[i] = (f32x4)0.0f;

    int arow = t >> 2, aseg = t & 3;
    int grow = rbase + arow;
    bool avalid = grow < N_NODES;
    int bn = t >> 1, bseg = t & 1;

    for (int k0 = 0; k0 < NFEAT; k0 += 64) {
        const float4* gs = (const float4*)(x + (size_t)grow * NFEAT + k0 + aseg * 16);
        __half* ad = sA + arow * G1_LDA + aseg * 16;
        #pragma unroll
        for (int i = 0; i < 4; i++) {
            float4 v = avalid ? gs[i] : make_float4(0.f, 0.f, 0.f, 0.f);
            __half2 h0 = __float22half2_rn(make_float2(v.x, v.y));
            __half2 h1 = __float22half2_rn(make_float2(v.z, v.w));
            uint2 st;
            st.x = __builtin_bit_cast(unsigned int, h0);
            st.y = __builtin_bit_cast(unsigned int, h1);
            *(uint2*)(ad + i * 4) = st;
        }
        const uint4* ws4 = (const uint4*)(w1t + bn * NFEAT + k0 + bseg * 32);
        uint4* bd = (uint4*)(sB + bn * G1_LDB + bseg * 32);
        #pragma unroll
        for (int i = 0; i < 4; i++) bd[i] = ws4[i];
        __syncthreads();
        #pragma unroll
        for (int kk = 0; kk < 64; kk += 32) {
            f16x8 af = *(const f16x8*)(sA + (wv * 16 + m) * G1_LDA + kk + quad * 8);
            #pragma unroll
            for (int t8 = 0; t8 < 8; t8++) {
                f16x8 bf = *(const f16x8*)(sB + (t8 * 16 + m) * G1_LDB + kk + quad * 8);
                acc[t8] = __builtin_amdgcn_mfma_f32_16x16x32_f16(af, bf, acc[t8], 0, 0, 0);
            }
        }
        __syncthreads();
    }
    // pre-scale each output row by dinv[row] while packing (rows >= N_NODES have dinv=0 -> zero rows)
    float di4[4];
    #pragma unroll
    for (int r = 0; r < 4; r++) di4[r] = dinv[rbase + wv * 16 + quad * 4 + r];
    __half* eb = smem;
    #pragma unroll
    for (int t8 = 0; t8 < 8; t8++) {
        #pragma unroll
        for (int r = 0; r < 4; r++)
            eb[(wv * 16 + quad * 4 + r) * G1_LDE + t8 * 16 + m] = __float2half(acc[t8][r] * di4[r]);
    }
    __syncthreads();
    {   // unconditional store: grid covers exactly NPAD rows; dummy rows are zeros
        const uint4* es = (const uint4*)(eb + arow * G1_LDE + aseg * 32);
        uint4* od = (uint4*)(h1h + (size_t)grow * NHID + aseg * 32);
        #pragma unroll
        for (int i = 0; i < 4; i++) od[i] = es[i];
    }
}

// ---------------- GEMM2 (MFMA): h2 planes = (h1p @ W2) * dinv[row] ----------------
// planeA: cls 0..31 as 64B rows (3.2MB); planeB: cls 32..39 as 16B rows (0.8MB)
#define G2_LDA 136
#define G2_LDB 136
#define G2_LDE 72
__global__ __launch_bounds__(256) void k_gemm2(const __half* __restrict__ h1p,
                                               const __half* __restrict__ w2t,
                                               const float* __restrict__ dinv,
                                               __half* __restrict__ h2pl) {
    __shared__ __half smem[64 * G2_LDA + 48 * G2_LDB];  // 30.5 KB
    __half* sA = smem;
    __half* sB = smem + 64 * G2_LDA;
    int t = threadIdx.x;
    int rbase = blockIdx.x * 64;
    int lane = t & 63, wv = t >> 6;
    int m = lane & 15, quad = lane >> 4;
    f32x4 acc[3];
    #pragma unroll
    for (int i = 0; i < 3; i++) acc[i] = (f32x4)0.0f;

    int arow = t >> 2, aseg = t & 3;
    int grow = rbase + arow;
    bool avalid = grow < N_NODES;

    #pragma unroll
    for (int i = 0; i < 3; i++) {
        int idx = t + i * 256;
        int n = idx >> 4, seg = idx & 15;
        *(uint4*)(sB + n * G2_LDB + seg * 8) = *(const uint4*)(w2t + n * NHID + seg * 8);
    }
    {
        const uint4* gs = (const uint4*)(h1p + (size_t)grow * NHID + aseg * 32);
        uint4* ad = (uint4*)(sA + arow * G2_LDA + aseg * 32);
        uint4 z; z.x = z.y = z.z = z.w = 0;
        #pragma unroll
        for (int i = 0; i < 4; i++) ad[i] = avalid ? gs[i] : z;
    }
    __syncthreads();
    #pragma unroll
    for (int kk = 0; kk < 128; kk += 32) {
        f16x8 af = *(const f16x8*)(sA + (wv * 16 + m) * G2_LDA + kk + quad * 8);
        #pragma unroll
        for (int t3 = 0; t3 < 3; t3++) {
            f16x8 bf = *(const f16x8*)(sB + (t3 * 16 + m) * G2_LDB + kk + quad * 8);
            acc[t3] = __builtin_amdgcn_mfma_f32_16x16x32_f16(af, bf, acc[t3], 0, 0, 0);
        }
    }
    __syncthreads();
    float di4[4];
    #pragma unroll
    for (int r = 0; r < 4; r++) di4[r] = dinv[rbase + wv * 16 + quad * 4 + r];
    __half* eb = smem;
    #pragma unroll
    for (int t3 = 0; t3 < 3; t3++) {
        #pragma unroll
        for (int r = 0; r < 4; r++)
            eb[(wv * 16 + quad * 4 + r) * G2_LDE + t3 * 16 + m] = __float2half(acc[t3][r] * di4[r]);
    }
    __syncthreads();
    __half* pA = h2pl;
    __half* pB = h2pl + (size_t)NPAD * 32;
    #pragma unroll
    for (int i = 0; i < 2; i++) {
        int idx = t + i * 256;
        int row = idx >> 3, seg = idx & 7;
        int gr = rbase + row;   // unconditional: dummy rows store zeros (acc=0, di=0)
        if (seg <= 4) {
            uint4 v = *(const uint4*)(eb + row * G2_LDE + seg * 8);
            if (seg < 4) ((uint4*)pA)[(size_t)gr * 4 + seg] = v;
            else        ((uint4*)pB)[gr] = v;
        }
    }
}

__device__ __forceinline__ void acc8f(float* acc, uint4 v, float d) {
    float2 a0 = __half22float2(__builtin_bit_cast(__half2, v.x));
    float2 a1 = __half22float2(__builtin_bit_cast(__half2, v.y));
    float2 a2 = __half22float2(__builtin_bit_cast(__half2, v.z));
    float2 a3 = __half22float2(__builtin_bit_cast(__half2, v.w));
    acc[0] = fmaf(a0.x, d, acc[0]); acc[1] = fmaf(a0.y, d, acc[1]);
    acc[2] = fmaf(a1.x, d, acc[2]); acc[3] = fmaf(a1.y, d, acc[3]);
    acc[4] = fmaf(a2.x, d, acc[4]); acc[5] = fmaf(a2.y, d, acc[5]);
    acc[6] = fmaf(a3.x, d, acc[6]); acc[7] = fmaf(a3.y, d, acc[7]);
}

// ---------------- agg1: round-10 structure (UNCHANGED, ~52 us control) ----------------
__global__ __launch_bounds__(64) void k_agg1(const __half* __restrict__ h1h,
                                             const float* __restrict__ dinv,
                                             const int* __restrict__ row_beg,
                                             const int* __restrict__ row_cnt,
                                             const int* __restrict__ esrc,
                                             const float* __restrict__ b1,
                                             const float* __restrict__ mask,
                                             __half* __restrict__ h1p) {
    int i = blockIdx.x;
    int lane = threadIdx.x;
    int q = lane >> 4;
    int fl = lane & 15;
    const uint4* hv4 = (const uint4*)h1h;
    float di = dinv[i];
    __half2 hacc[4];
    __half2 hz = __half2half2(__float2half(0.0f));
    hacc[0] = hz; hacc[1] = hz; hacc[2] = hz; hacc[3] = hz;
    int s0 = row_beg[i], cnt = row_cnt[i];
    for (int base = 0; base < cnt; base += 64) {
        int idx = base + lane;
        int sv = (idx < cnt) ? __builtin_nontemporal_load(&esrc[s0 + idx]) : DUMMY;
        int n = min(64, cnt - base);
        int nr = (n + 31) & ~31;
        for (int j = 0; j < nr; j += 32) {
            int ss[8]; uint4 vv[8];
            #pragma unroll
            for (int k = 0; k < 8; k++) ss[k] = __shfl(sv, j + 4 * k + q);
            #pragma unroll
            for (int k = 0; k < 8; k++) vv[k] = hv4[(size_t)ss[k] * 16 + fl];
            #pragma unroll
            for (int k = 0; k < 8; k++) {
                hacc[0] = __hadd2(hacc[0], __builtin_bit_cast(__half2, vv[k].x));
                hacc[1] = __hadd2(hacc[1], __builtin_bit_cast(__half2, vv[k].y));
                hacc[2] = __hadd2(hacc[2], __builtin_bit_cast(__half2, vv[k].z));
                hacc[3] = __hadd2(hacc[3], __builtin_bit_cast(__half2, vv[k].w));
            }
        }
    }
    #pragma unroll
    for (int d = 16; d <= 32; d <<= 1) {
        #pragma unroll
        for (int r = 0; r < 4; r++) {
            unsigned int u = __shfl_xor(__builtin_bit_cast(unsigned int, hacc[r]), d);
            hacc[r] = __hadd2(hacc[r], __builtin_bit_cast(__half2, u));
        }
    }
    if (q == 0) {
        float acc[8];
        #pragma unroll
        for (int r = 0; r < 4; r++) {
            float2 f = __half22float2(hacc[r]);
            acc[2 * r] = f.x; acc[2 * r + 1] = f.y;
        }
        uint4 sv4 = hv4[(size_t)i * 16 + fl];      // self row (already *dinv[i])
        acc8f(acc, sv4, 1.0f);
        float4 bb0 = ((const float4*)b1)[fl * 2];
        float4 bb1 = ((const float4*)b1)[fl * 2 + 1];
        const fv4* mrow = (const fv4*)(mask + (size_t)i * NHID);
        fv4 mm0 = __builtin_nontemporal_load(&mrow[fl * 2]);
        fv4 mm1 = __builtin_nontemporal_load(&mrow[fl * 2 + 1]);
        float o0 = fmaxf(fmaf(acc[0], di, bb0.x), 0.f) * mm0[0];
        float o1 = fmaxf(fmaf(acc[1], di, bb0.y), 0.f) * mm0[1];
        float o2 = fmaxf(fmaf(acc[2], di, bb0.z), 0.f) * mm0[2];
        float o3 = fmaxf(fmaf(acc[3], di, bb0.w), 0.f) * mm0[3];
        float o4 = fmaxf(fmaf(acc[4], di, bb1.x), 0.f) * mm1[0];
        float o5 = fmaxf(fmaf(acc[5], di, bb1.y), 0.f) * mm1[1];
        float o6 = fmaxf(fmaf(acc[6], di, bb1.z), 0.f) * mm1[2];
        float o7 = fmaxf(fmaf(acc[7], di, bb1.w), 0.f) * mm1[3];
        __half2 p0 = __float22half2_rn(make_float2(o0, o1));
        __half2 p1 = __float22half2_rn(make_float2(o2, o3));
        __half2 p2 = __float22half2_rn(make_float2(o4, o5));
        __half2 p3 = __float22half2_rn(make_float2(o6, o7));
        uv4 st;
        st[0] = __builtin_bit_cast(unsigned int, p0);
        st[1] = __builtin_bit_cast(unsigned int, p1);
        st[2] = __builtin_bit_cast(unsigned int, p2);
        st[3] = __builtin_bit_cast(unsigned int, p3);
        __builtin_nontemporal_store(st, &((uv4*)h1p)[(size_t)i * 16 + fl]);
    }
}

// ---------------- agg2: 2 nodes/wave (32 lanes each), slim planes, + log_softmax ----------------
// per half-wave: 8 edge-slots (g2) x 4 chunks (fl) for planeA; per-lane planeB.
__global__ __launch_bounds__(64) void k_agg2(const __half* __restrict__ h2pl,
                                             const float* __restrict__ dinv,
                                             const int* __restrict__ row_beg,
                                             const int* __restrict__ row_cnt,
                                             const int* __restrict__ esrc,
                                             const float* __restrict__ b2,
                                             float* __restrict__ out) {
    int lane = threadIdx.x;
    int h = lane >> 5;        // node half (0/1)
    int sub = lane & 31;
    int i = blockIdx.x * 2 + h;   // N_NODES = 2*25000 exactly
    int g2 = sub >> 2;        // 8 edge slots per half
    int fl = sub & 3;         // 16B chunk of 64B planeA row
    const uint4* pA = (const uint4*)h2pl;
    const uint4* pB = (const uint4*)(h2pl + (size_t)NPAD * 32);
    float di = dinv[i];
    __half2 a0[4], a1[4];
    __half2 hz = __half2half2(__float2half(0.0f));
    #pragma unroll
    for (int r = 0; r < 4; r++) { a0[r] = hz; a1[r] = hz; }
    int s0 = row_beg[i], cnt = row_cnt[i];
    for (int base = 0; base < cnt; base += 32) {
        int idx = base + sub;
        int sv = (idx < cnt) ? __builtin_nontemporal_load(&esrc[s0 + idx]) : DUMMY;
        // planeB: one edge per lane (16B row, zeros at DUMMY)
        uint4 v1 = pB[sv];
        a1[0] = __hadd2(a1[0], __builtin_bit_cast(__half2, v1.x));
        a1[1] = __hadd2(a1[1], __builtin_bit_cast(__half2, v1.y));
        a1[2] = __hadd2(a1[2], __builtin_bit_cast(__half2, v1.z));
        a1[3] = __hadd2(a1[3], __builtin_bit_cast(__half2, v1.w));
        // planeA: 8 slots x 4 j-steps = 32 edges per batch
        int n = min(32, cnt - base);
        int nr = (n + 7) & ~7;
        for (int j = 0; j < nr; j += 8) {
            int ss = __shfl(sv, h * 32 + j + g2);
            uint4 vv = pA[(size_t)ss * 4 + fl];
            a0[0] = __hadd2(a0[0], __builtin_bit_cast(__half2, vv.x));
            a0[1] = __hadd2(a0[1], __builtin_bit_cast(__half2, vv.y));
            a0[2] = __hadd2(a0[2], __builtin_bit_cast(__half2, vv.z));
            a0[3] = __hadd2(a0[3], __builtin_bit_cast(__half2, vv.w));
        }
    }
    // a1: half-wave reduce (strides 1..16); a0: group reduce (strides 4..16)
    #pragma unroll
    for (int d = 1; d <= 16; d <<= 1) {
        #pragma unroll
        for (int r = 0; r < 4; r++) {
            unsigned int u = __shfl_xor(__builtin_bit_cast(unsigned int, a1[r]), d);
            a1[r] = __hadd2(a1[r], __builtin_bit_cast(__half2, u));
            if (d >= 4) {
                unsigned int u0 = __shfl_xor(__builtin_bit_cast(unsigned int, a0[r]), d);
                a0[r] = __hadd2(a0[r], __builtin_bit_cast(__half2, u0));
            }
        }
    }
    float val0[8], val1[8];
    if (g2 == 0) {   // sub 0..3: classes [fl*8, fl*8+8)
        float acc[8];
        #pragma unroll
        for (int r = 0; r < 4; r++) {
            float2 f = __half22float2(a0[r]);
            acc[2 * r] = f.x; acc[2 * r + 1] = f.y;
        }
        uint4 s4 = pA[(size_t)i * 4 + fl];          // self (pre-scaled)
        acc8f(acc, s4, 1.0f);
        float4 bb0 = *(const float4*)(b2 + fl * 8);
        float4 bb1 = *(const float4*)(b2 + fl * 8 + 4);
        val0[0] = fmaf(acc[0], di, bb0.x);
        val0[1] = fmaf(acc[1], di, bb0.y);
        val0[2] = fmaf(acc[2], di, bb0.z);
        val0[3] = fmaf(acc[3], di, bb0.w);
        val0[4] = fmaf(acc[4], di, bb1.x);
        val0[5] = fmaf(acc[5], di, bb1.y);
        val0[6] = fmaf(acc[6], di, bb1.z);
        val0[7] = fmaf(acc[7], di, bb1.w);
    }
    if (sub == 0) {  // classes 32..39
        float acc[8];
        #pragma unroll
        for (int r = 0; r < 4; r++) {
            float2 f = __half22float2(a1[r]);
            acc[2 * r] = f.x; acc[2 * r + 1] = f.y;
        }
        acc8f(acc, pB[i], 1.0f);                    // self (pre-scaled)
        float4 bb0 = *(const float4*)(b2 + 32);
        float4 bb1 = *(const float4*)(b2 + 36);
        val1[0] = fmaf(acc[0], di, bb0.x);
        val1[1] = fmaf(acc[1], di, bb0.y);
        val1[2] = fmaf(acc[2], di, bb0.z);
        val1[3] = fmaf(acc[3], di, bb0.w);
        val1[4] = fmaf(acc[4], di, bb1.x);
        val1[5] = fmaf(acc[5], di, bb1.y);
        val1[6] = fmaf(acc[6], di, bb1.z);
        val1[7] = fmaf(acc[7], di, bb1.w);
    }
    // softmax over 40 classes per half: sub 0..3 hold val0, sub 0 additionally val1
    float m = -INFINITY;
    if (g2 == 0) {
        #pragma unroll
        for (int k = 0; k < 8; k++) m = fmaxf(m, val0[k]);
    }
    if (sub == 0) {
        #pragma unroll
        for (int k = 0; k < 8; k++) m = fmaxf(m, val1[k]);
    }
    m = fmaxf(m, __shfl_xor(m, 1));
    m = fmaxf(m, __shfl_xor(m, 2));
    float ssum = 0.f;
    if (g2 == 0) {
        #pragma unroll
        for (int k = 0; k < 8; k++) ssum += expf(val0[k] - m);
    }
    if (sub == 0) {
        #pragma unroll
        for (int k = 0; k < 8; k++) ssum += expf(val1[k] - m);
    }
    ssum += __shfl_xor(ssum, 1);
    ssum += __shfl_xor(ssum, 2);
    if (g2 == 0) {
        float ls = m + logf(ssum);
        float4 r0 = make_float4(val0[0] - ls, val0[1] - ls, val0[2] - ls, val0[3] - ls);
        float4 r1 = make_float4(val0[4] - ls, val0[5] - ls, val0[6] - ls, val0[7] - ls);
        float4* orow = (float4*)(out + (size_t)i * NCLASS + fl * 8);
        orow[0] = r0;
        orow[1] = r1;
        if (sub == 0) {
            float4 r2 = make_float4(val1[0] - ls, val1[1] - ls, val1[2] - ls, val1[3] - ls);
            float4 r3 = make_float4(val1[4] - ls, val1[5] - ls, val1[6] - ls, val1[7] - ls);
            float4* orow1 = (float4*)(out + (size_t)i * NCLASS + 32);
            orow1[0] = r2;
            orow1[1] = r3;
        }
    }
}

extern "C" void kernel_launch(void* const* d_in, const int* in_sizes, int n_in,
                              void* d_out, int out_size, void* d_ws, size_t ws_size,
                              hipStream_t stream) {
    const float* x    = (const float*)d_in[0];
    const int*   ei   = (const int*)d_in[1];
    const float* W1   = (const float*)d_in[2];
    const float* b1   = (const float*)d_in[3];
    const float* W2   = (const float*)d_in[4];
    const float* b2   = (const float*)d_in[5];
    const float* mask = (const float*)d_in[6];
    float* out = (float*)d_out;

    const int* src = ei;
    const int* dst = ei + N_EDGES;

    char* ws = (char*)d_ws;
    size_t off = 0;
    __half* h1p    = (__half*)(ws + off); off += (size_t)NPAD * NHID * 2;      // 12.8 MB
    __half* h1h    = (__half*)(ws + off); off += (size_t)NPAD * NHID * 2;      // 12.8 MB
    int*    esrc   = (int*)   (ws + off); off += (size_t)NBUCK * CAP * 4 + 256;// 8.0 MB
    float*  dinv   = (float*) (ws + off); off += (size_t)NPAD * 4;
    int*   row_beg = (int*)   (ws + off); off += (size_t)NPAD * 4;
    int*   row_cnt = (int*)   (ws + off); off += (size_t)NPAD * 4;
    int*    gcur   = (int*)   (ws + off); off += 2048;
    __half* w1t    = (__half*)(ws + off); off += 128 * 256 * 2;                // 64 KB
    __half* w2t    = (__half*)(ws + off); off += 48 * 128 * 2;                 // 12 KB

    unsigned int* packed = (unsigned int*)h1p;  // binA/binB lifetime only
    __half* h2pl = h1h;                          // gemm2/agg2 lifetime (4.0 MB used)

    k_prep<<<196, 256, 0, stream>>>(W1, W2, w1t, w2t, gcur, dinv);
    k_binA<<<(N_EDGES + EPB - 1) / EPB, 256, 0, stream>>>(src, dst, gcur, packed);
    k_binB<<<NBUCK, 256, 0, stream>>>(gcur, packed, esrc, row_beg, row_cnt, dinv);

    k_gemm1<<<NPAD / 64, 256, 0, stream>>>(x, w1t, dinv, h1h);
    k_agg1<<<N_NODES, 64, 0, stream>>>(h1h, dinv, row_beg, row_cnt, esrc, b1, mask, h1p);
    k_gemm2<<<NPAD / 64, 256, 0, stream>>>(h1p, w2t, dinv, h2pl);
    k_agg2<<<N_NODES / 2, 64, 0, stream>>>(h2pl, dinv, row_beg, row_cnt, esrc, b2, out);
}

// Round 13
// 259.161 us; speedup vs baseline: 7.7464x; 1.0014x over previous
//
#include <hip/hip_runtime.h>
#include <hip/hip_fp16.h>
#include <math.h>

#define N_NODES 50000
#define N_EDGES 1600000
#define NFEAT 256
#define NHID 128
#define NCLASS 40

#define NPAD 50048           // grid-rounded node count (dummy zero rows >= N_NODES)
#define DUMMY N_NODES        // index of a guaranteed-zero table row

#define BSHIFT 7
#define NBUCK 391            // ceil(50000 / 128)
#define CAP 5120             // per-bucket capacity (mean 4092)
#define EPB 4096             // edges per binA block -> 391 blocks

typedef _Float16 f16x8 __attribute__((ext_vector_type(8)));
typedef float f32x4 __attribute__((ext_vector_type(4)));
typedef float fv4 __attribute__((ext_vector_type(4)));      // nt-capable float4
typedef unsigned int uv4 __attribute__((ext_vector_type(4))); // nt-capable uint4

// ---------------- pass A: coarse binning by dst>>7 ----------------
__global__ __launch_bounds__(256) void k_binA(const int* __restrict__ src,
                                              const int* __restrict__ dst,
                                              int* __restrict__ gcur,
                                              unsigned int* __restrict__ packed) {
    __shared__ int lhist[NBUCK];
    __shared__ int lbase[NBUCK];
    __shared__ int lcur[NBUCK];
    int t = threadIdx.x;
    for (int i = t; i < NBUCK; i += 256) { lhist[i] = 0; lcur[i] = 0; }
    __syncthreads();
    int e0 = blockIdx.x * EPB;
    int e1 = min(e0 + EPB, N_EDGES);
    for (int e = e0 + t; e < e1; e += 256) {
        int b = dst[e] >> BSHIFT;
        atomicAdd(&lhist[b], 1);
    }
    __syncthreads();
    for (int i = t; i < NBUCK; i += 256)
        lbase[i] = atomicAdd(&gcur[i], lhist[i]);
    __syncthreads();
    for (int e = e0 + t; e < e1; e += 256) {
        int d = dst[e];
        int b = d >> BSHIFT;
        int r = atomicAdd(&lcur[b], 1);
        int pos = lbase[b] + r;
        if (pos < CAP)
            packed[(size_t)b * CAP + pos] =
                ((unsigned int)src[e] << BSHIFT) | (unsigned int)(d & 127);
    }
}

// ---------------- pass B: in-LDS fine sort per bucket + CSR metadata + dinv ----------------
__global__ __launch_bounds__(256) void k_binB(const int* __restrict__ gcur,
                                              const unsigned int* __restrict__ packed,
                                              int* __restrict__ esrc,
                                              int* __restrict__ row_beg,
                                              int* __restrict__ row_cnt,
                                              float* __restrict__ dinv) {
    __shared__ unsigned int sp[CAP];     // 20 KB
    __shared__ int hist[128];
    __shared__ int scan[128];
    __shared__ int cur[128];
    int b = blockIdx.x;
    int t = threadIdx.x;
    int cnt = min(gcur[b], CAP);
    if (t < 128) { hist[t] = 0; cur[t] = 0; }
    __syncthreads();
    const unsigned int* pin = packed + (size_t)b * CAP;
    for (int i = t; i < cnt; i += 256) {
        unsigned int w = pin[i];
        sp[i] = w;
        atomicAdd(&hist[w & 127], 1);
    }
    __syncthreads();
    if (t == 0) {
        int s = 0;
        for (int i = 0; i < 128; i++) { scan[i] = s; s += hist[i]; }
    }
    __syncthreads();
    for (int i = t; i < cnt; i += 256) {
        unsigned int w = sp[i];
        int dl = (int)(w & 127u);
        int r = atomicAdd(&cur[dl], 1);
        esrc[(size_t)b * CAP + scan[dl] + r] = (int)(w >> BSHIFT);
    }
    if (t < 128) {
        int node = b * 128 + t;
        if (node < N_NODES) {
            row_beg[node] = b * CAP + scan[t];
            row_cnt[node] = hist[t];
            dinv[node] = rsqrtf((float)(hist[t] + 1));
        }
    }
}

// ---------------- prep: W transposes to fp16 + gcur zero + dinv tail zero ----------------
__global__ __launch_bounds__(256) void k_prep(const float* __restrict__ W1,
                                              const float* __restrict__ W2,
                                              __half* __restrict__ w1t,
                                              __half* __restrict__ w2t,
                                              int* __restrict__ gcur,
                                              float* __restrict__ dinv) {
    int t = blockIdx.x * 256 + threadIdx.x;
    if (t < NBUCK) gcur[t] = 0;
    if (t >= N_NODES && t < NPAD) dinv[t] = 0.0f;   // dummy rows scale to zero
    if (t < 128 * 256) {
        int n = t >> 8, k = t & 255;
        w1t[t] = __float2half(W1[k * NHID + n]);
    }
    if (t < 48 * 128) {
        int n = t >> 7, k = t & 127;
        w2t[t] = __float2half(n < NCLASS ? W2[k * NCLASS + n] : 0.0f);
    }
}

// ---------------- GEMM1 (MFMA): h1h(fp16) = (x @ W1) * dinv[row]  (pre-scaled table) ----------------
#define G1_LDA 72
#define G1_LDB 72
#define G1_LDE 136
__global__ __launch_bounds__(256) void k_gemm1(const float* __restrict__ x,
                                               const __half* __restrict__ w1t,
                                               const float* __restrict__ dinv,
                                               __half* __restrict__ h1h) {
    __shared__ __half smem[64 * G1_LDA + 128 * G1_LDB];   // 27.6 KB
    __half* sA = smem;
    __half* sB = smem + 64 * G1_LDA;
    int t = threadIdx.x;
    int rbase = blockIdx.x * 64;
    int lane = t & 63, wv = t >> 6;
    int m = lane & 15, quad = lane >> 4;
    f32x4 acc[8];
    #pragma unroll
    for (int i = 0; i < 8; i++) acc[i] = (f32x4)0.0f;

    int arow = t >> 2, aseg = t & 3;
    int grow = rbase + arow;
    bool avalid = grow < N_NODES;
    int bn = t >> 1, bseg = t & 1;

    for (int k0 = 0; k0 < NFEAT; k0 += 64) {
        const float4* gs = (const float4*)(x + (size_t)grow * NFEAT + k0 + aseg * 16);
        __half* ad = sA + arow * G1_LDA + aseg * 16;
        #pragma unroll
        for (int i = 0; i < 4; i++) {
            float4 v = avalid ? gs[i] : make_float4(0.f, 0.f, 0.f, 0.f);
            __half2 h0 = __float22half2_rn(make_float2(v.x, v.y));
            __half2 h1 = __float22half2_rn(make_float2(v.z, v.w));
            uint2 st;
            st.x = __builtin_bit_cast(unsigned int, h0);
            st.y = __builtin_bit_cast(unsigned int, h1);
            *(uint2*)(ad + i * 4) = st;
        }
        const uint4* ws4 = (const uint4*)(w1t + bn * NFEAT + k0 + bseg * 32);
        uint4* bd = (uint4*)(sB + bn * G1_LDB + bseg * 32);
        #pragma unroll
        for (int i = 0; i < 4; i++) bd[i] = ws4[i];
        __syncthreads();
        #pragma unroll
        for (int kk = 0; kk < 64; kk += 32) {
            f16x8 af = *(const f16x8*)(sA + (wv * 16 + m) * G1_LDA + kk + quad * 8);
            #pragma unroll
            for (int t8 = 0; t8 < 8; t8++) {
                f16x8 bf = *(const f16x8*)(sB + (t8 * 16 + m) * G1_LDB + kk + quad * 8);
                acc[t8] = __builtin_amdgcn_mfma_f32_16x16x32_f16(af, bf, acc[t8], 0, 0, 0);
            }
        }
        __syncthreads();
    }
    // pre-scale each output row by dinv[row] while packing (rows >= N_NODES have dinv=0 -> zero rows)
    float di4[4];
    #pragma unroll
    for (int r = 0; r < 4; r++) di4[r] = dinv[rbase + wv * 16 + quad * 4 + r];
    __half* eb = smem;
    #pragma unroll
    for (int t8 = 0; t8 < 8; t8++) {
        #pragma unroll
        for (int r = 0; r < 4; r++)
            eb[(wv * 16 + quad * 4 + r) * G1_LDE + t8 * 16 + m] = __float2half(acc[t8][r] * di4[r]);
    }
    __syncthreads();
    {   // unconditional store: grid covers exactly NPAD rows; dummy rows are zeros
        const uint4* es = (const uint4*)(eb + arow * G1_LDE + aseg * 32);
        uint4* od = (uint4*)(h1h + (size_t)grow * NHID + aseg * 32);
        #pragma unroll
        for (int i = 0; i < 4; i++) od[i] = es[i];
    }
}

// ---------------- GEMM2 (MFMA): h2 planes = (h1p @ W2) * dinv[row] ----------------
// planeA: cls 0..31 as 64B rows (3.2MB); planeB: cls 32..39 as 16B rows (0.8MB)
#define G2_LDA 136
#define G2_LDB 136
#define G2_LDE 72
__global__ __launch_bounds__(256) void k_gemm2(const __half* __restrict__ h1p,
                                               const __half* __restrict__ w2t,
                                               const float* __restrict__ dinv,
                                               __half* __restrict__ h2pl) {
    __shared__ __half smem[64 * G2_LDA + 48 * G2_LDB];  // 30.5 KB
    __half* sA = smem;
    __half* sB = smem + 64 * G2_LDA;
    int t = threadIdx.x;
    int rbase = blockIdx.x * 64;
    int lane = t & 63, wv = t >> 6;
    int m = lane & 15, quad = lane >> 4;
    f32x4 acc[3];
    #pragma unroll
    for (int i = 0; i < 3; i++) acc[i] = (f32x4)0.0f;

    int arow = t >> 2, aseg = t & 3;
    int grow = rbase + arow;
    bool avalid = grow < N_NODES;

    #pragma unroll
    for (int i = 0; i < 3; i++) {
        int idx = t + i * 256;
        int n = idx >> 4, seg = idx & 15;
        *(uint4*)(sB + n * G2_LDB + seg * 8) = *(const uint4*)(w2t + n * NHID + seg * 8);
    }
    {
        const uint4* gs = (const uint4*)(h1p + (size_t)grow * NHID + aseg * 32);
        uint4* ad = (uint4*)(sA + arow * G2_LDA + aseg * 32);
        uint4 z; z.x = z.y = z.z = z.w = 0;
        #pragma unroll
        for (int i = 0; i < 4; i++) ad[i] = avalid ? gs[i] : z;
    }
    __syncthreads();
    #pragma unroll
    for (int kk = 0; kk < 128; kk += 32) {
        f16x8 af = *(const f16x8*)(sA + (wv * 16 + m) * G2_LDA + kk + quad * 8);
        #pragma unroll
        for (int t3 = 0; t3 < 3; t3++) {
            f16x8 bf = *(const f16x8*)(sB + (t3 * 16 + m) * G2_LDB + kk + quad * 8);
            acc[t3] = __builtin_amdgcn_mfma_f32_16x16x32_f16(af, bf, acc[t3], 0, 0, 0);
        }
    }
    __syncthreads();
    float di4[4];
    #pragma unroll
    for (int r = 0; r < 4; r++) di4[r] = dinv[rbase + wv * 16 + quad * 4 + r];
    __half* eb = smem;
    #pragma unroll
    for (int t3 = 0; t3 < 3; t3++) {
        #pragma unroll
        for (int r = 0; r < 4; r++)
            eb[(wv * 16 + quad * 4 + r) * G2_LDE + t3 * 16 + m] = __float2half(acc[t3][r] * di4[r]);
    }
    __syncthreads();
    __half* pA = h2pl;
    __half* pB = h2pl + (size_t)NPAD * 32;
    #pragma unroll
    for (int i = 0; i < 2; i++) {
        int idx = t + i * 256;
        int row = idx >> 3, seg = idx & 7;
        int gr = rbase + row;   // unconditional: dummy rows store zeros (acc=0, di=0)
        if (seg <= 4) {
            uint4 v = *(const uint4*)(eb + row * G2_LDE + seg * 8);
            if (seg < 4) ((uint4*)pA)[(size_t)gr * 4 + seg] = v;
            else        ((uint4*)pB)[gr] = v;
        }
    }
}

__device__ __forceinline__ void acc8f(float* acc, uint4 v, float d) {
    float2 a0 = __half22float2(__builtin_bit_cast(__half2, v.x));
    float2 a1 = __half22float2(__builtin_bit_cast(__half2, v.y));
    float2 a2 = __half22float2(__builtin_bit_cast(__half2, v.z));
    float2 a3 = __half22float2(__builtin_bit_cast(__half2, v.w));
    acc[0] = fmaf(a0.x, d, acc[0]); acc[1] = fmaf(a0.y, d, acc[1]);
    acc[2] = fmaf(a1.x, d, acc[2]); acc[3] = fmaf(a1.y, d, acc[3]);
    acc[4] = fmaf(a2.x, d, acc[4]); acc[5] = fmaf(a2.y, d, acc[5]);
    acc[6] = fmaf(a3.x, d, acc[6]); acc[7] = fmaf(a3.y, d, acc[7]);
}

// ---------------- agg1: 2 nodes/wave (32 lanes each), 8-deep gathers ----------------
// per half-wave: 2 edge-groups (g) x 16 row-chunks (fl); tails via DUMMY zero row.
__global__ __launch_bounds__(64) void k_agg1(const __half* __restrict__ h1h,
                                             const float* __restrict__ dinv,
                                             const int* __restrict__ row_beg,
                                             const int* __restrict__ row_cnt,
                                             const int* __restrict__ esrc,
                                             const float* __restrict__ b1,
                                             const float* __restrict__ mask,
                                             __half* __restrict__ h1p) {
    int lane = threadIdx.x;
    int h = lane >> 5;        // node half (0/1)
    int sub = lane & 31;
    int i = blockIdx.x * 2 + h;   // N_NODES = 2*25000 exactly
    int g = sub >> 4;         // 2 edge groups per half
    int fl = sub & 15;        // 16B chunk of the 256B row
    const uint4* hv4 = (const uint4*)h1h;
    float di = dinv[i];
    __half2 hacc[4];
    __half2 hz = __half2half2(__float2half(0.0f));
    hacc[0] = hz; hacc[1] = hz; hacc[2] = hz; hacc[3] = hz;
    int s0 = row_beg[i], cnt = row_cnt[i];
    for (int base = 0; base < cnt; base += 32) {
        int idx = base + sub;
        int sv = (idx < cnt) ? __builtin_nontemporal_load(&esrc[s0 + idx]) : DUMMY;
        int n = min(32, cnt - base);
        int nr = (n + 15) & ~15;
        for (int j = 0; j < nr; j += 16) {
            int ss[8]; uint4 vv[8];
            #pragma unroll
            for (int k = 0; k < 8; k++) ss[k] = __shfl(sv, h * 32 + j + 2 * k + g);
            #pragma unroll
            for (int k = 0; k < 8; k++) vv[k] = hv4[(size_t)ss[k] * 16 + fl];
            #pragma unroll
            for (int k = 0; k < 8; k++) {
                hacc[0] = __hadd2(hacc[0], __builtin_bit_cast(__half2, vv[k].x));
                hacc[1] = __hadd2(hacc[1], __builtin_bit_cast(__half2, vv[k].y));
                hacc[2] = __hadd2(hacc[2], __builtin_bit_cast(__half2, vv[k].z));
                hacc[3] = __hadd2(hacc[3], __builtin_bit_cast(__half2, vv[k].w));
            }
        }
    }
    // reduce across the 2 edge groups (stride 16, stays within half)
    #pragma unroll
    for (int r = 0; r < 4; r++) {
        unsigned int u = __shfl_xor(__builtin_bit_cast(unsigned int, hacc[r]), 16);
        hacc[r] = __hadd2(hacc[r], __builtin_bit_cast(__half2, u));
    }
    if (g == 0) {   // sub 0..15 of each half
        float acc[8];
        #pragma unroll
        for (int r = 0; r < 4; r++) {
            float2 f = __half22float2(hacc[r]);
            acc[2 * r] = f.x; acc[2 * r + 1] = f.y;
        }
        uint4 sv4 = hv4[(size_t)i * 16 + fl];      // self row (already *dinv[i])
        acc8f(acc, sv4, 1.0f);
        float4 bb0 = ((const float4*)b1)[fl * 2];
        float4 bb1 = ((const float4*)b1)[fl * 2 + 1];
        const fv4* mrow = (const fv4*)(mask + (size_t)i * NHID);
        fv4 mm0 = __builtin_nontemporal_load(&mrow[fl * 2]);
        fv4 mm1 = __builtin_nontemporal_load(&mrow[fl * 2 + 1]);
        float o0 = fmaxf(fmaf(acc[0], di, bb0.x), 0.f) * mm0[0];
        float o1 = fmaxf(fmaf(acc[1], di, bb0.y), 0.f) * mm0[1];
        float o2 = fmaxf(fmaf(acc[2], di, bb0.z), 0.f) * mm0[2];
        float o3 = fmaxf(fmaf(acc[3], di, bb0.w), 0.f) * mm0[3];
        float o4 = fmaxf(fmaf(acc[4], di, bb1.x), 0.f) * mm1[0];
        float o5 = fmaxf(fmaf(acc[5], di, bb1.y), 0.f) * mm1[1];
        float o6 = fmaxf(fmaf(acc[6], di, bb1.z), 0.f) * mm1[2];
        float o7 = fmaxf(fmaf(acc[7], di, bb1.w), 0.f) * mm1[3];
        __half2 p0 = __float22half2_rn(make_float2(o0, o1));
        __half2 p1 = __float22half2_rn(make_float2(o2, o3));
        __half2 p2 = __float22half2_rn(make_float2(o4, o5));
        __half2 p3 = __float22half2_rn(make_float2(o6, o7));
        uv4 st;
        st[0] = __builtin_bit_cast(unsigned int, p0);
        st[1] = __builtin_bit_cast(unsigned int, p1);
        st[2] = __builtin_bit_cast(unsigned int, p2);
        st[3] = __builtin_bit_cast(unsigned int, p3);
        __builtin_nontemporal_store(st, &((uv4*)h1p)[(size_t)i * 16 + fl]);
    }
}

// ---------------- agg2: 4 nodes/wave (16 lanes each), slim planes, + log_softmax ----------------
// per quarter-wave: 4 edge-slots (g2) x 4 chunks (fl) for planeA; per-lane planeB.
__global__ __launch_bounds__(64) void k_agg2(const __half* __restrict__ h2pl,
                                             const float* __restrict__ dinv,
                                             const int* __restrict__ row_beg,
                                             const int* __restrict__ row_cnt,
                                             const int* __restrict__ esrc,
                                             const float* __restrict__ b2,
                                             float* __restrict__ out) {
    int lane = threadIdx.x;
    int h = lane >> 4;        // node quarter (0..3)
    int sub = lane & 15;
    int i = blockIdx.x * 4 + h;   // N_NODES = 4*12500 exactly
    int g2 = sub >> 2;        // 4 edge slots per quarter
    int fl = sub & 3;         // 16B chunk of 64B planeA row
    const uint4* pA = (const uint4*)h2pl;
    const uint4* pB = (const uint4*)(h2pl + (size_t)NPAD * 32);
    float di = dinv[i];
    __half2 a0[4], a1[4];
    __half2 hz = __half2half2(__float2half(0.0f));
    #pragma unroll
    for (int r = 0; r < 4; r++) { a0[r] = hz; a1[r] = hz; }
    int s0 = row_beg[i], cnt = row_cnt[i];
    for (int base = 0; base < cnt; base += 16) {
        int idx = base + sub;
        int sv = (idx < cnt) ? __builtin_nontemporal_load(&esrc[s0 + idx]) : DUMMY;
        // planeB: one edge per lane (16B row, zeros at DUMMY)
        uint4 v1 = pB[sv];
        a1[0] = __hadd2(a1[0], __builtin_bit_cast(__half2, v1.x));
        a1[1] = __hadd2(a1[1], __builtin_bit_cast(__half2, v1.y));
        a1[2] = __hadd2(a1[2], __builtin_bit_cast(__half2, v1.z));
        a1[3] = __hadd2(a1[3], __builtin_bit_cast(__half2, v1.w));
        // planeA: 4 slots x 4 j-steps = 16 edges per batch
        int n = min(16, cnt - base);
        int nr = (n + 3) & ~3;
        for (int j = 0; j < nr; j += 4) {
            int ss = __shfl(sv, h * 16 + j + g2);
            uint4 vv = pA[(size_t)ss * 4 + fl];
            a0[0] = __hadd2(a0[0], __builtin_bit_cast(__half2, vv.x));
            a0[1] = __hadd2(a0[1], __builtin_bit_cast(__half2, vv.y));
            a0[2] = __hadd2(a0[2], __builtin_bit_cast(__half2, vv.z));
            a0[3] = __hadd2(a0[3], __builtin_bit_cast(__half2, vv.w));
        }
    }
    // a1: quarter reduce (strides 1..8); a0: group reduce (strides 4, 8)
    #pragma unroll
    for (int d = 1; d <= 8; d <<= 1) {
        #pragma unroll
        for (int r = 0; r < 4; r++) {
            unsigned int u = __shfl_xor(__builtin_bit_cast(unsigned int, a1[r]), d);
            a1[r] = __hadd2(a1[r], __builtin_bit_cast(__half2, u));
            if (d >= 4) {
                unsigned int u0 = __shfl_xor(__builtin_bit_cast(unsigned int, a0[r]), d);
                a0[r] = __hadd2(a0[r], __builtin_bit_cast(__half2, u0));
            }
        }
    }
    float val0[8], val1[8];
    if (g2 == 0) {   // sub 0..3: classes [fl*8, fl*8+8)
        float acc[8];
        #pragma unroll
        for (int r = 0; r < 4; r++) {
            float2 f = __half22float2(a0[r]);
            acc[2 * r] = f.x; acc[2 * r + 1] = f.y;
        }
        uint4 s4 = pA[(size_t)i * 4 + fl];          // self (pre-scaled)
        acc8f(acc, s4, 1.0f);
        float4 bb0 = *(const float4*)(b2 + fl * 8);
        float4 bb1 = *(const float4*)(b2 + fl * 8 + 4);
        val0[0] = fmaf(acc[0], di, bb0.x);
        val0[1] = fmaf(acc[1], di, bb0.y);
        val0[2] = fmaf(acc[2], di, bb0.z);
        val0[3] = fmaf(acc[3], di, bb0.w);
        val0[4] = fmaf(acc[4], di, bb1.x);
        val0[5] = fmaf(acc[5], di, bb1.y);
        val0[6] = fmaf(acc[6], di, bb1.z);
        val0[7] = fmaf(acc[7], di, bb1.w);
    }
    if (sub == 0) {  // classes 32..39
        float acc[8];
        #pragma unroll
        for (int r = 0; r < 4; r++) {
            float2 f = __half22float2(a1[r]);
            acc[2 * r] = f.x; acc[2 * r + 1] = f.y;
        }
        acc8f(acc, pB[i], 1.0f);                    // self (pre-scaled)
        float4 bb0 = *(const float4*)(b2 + 32);
        float4 bb1 = *(const float4*)(b2 + 36);
        val1[0] = fmaf(acc[0], di, bb0.x);
        val1[1] = fmaf(acc[1], di, bb0.y);
        val1[2] = fmaf(acc[2], di, bb0.z);
        val1[3] = fmaf(acc[3], di, bb0.w);
        val1[4] = fmaf(acc[4], di, bb1.x);
        val1[5] = fmaf(acc[5], di, bb1.y);
        val1[6] = fmaf(acc[6], di, bb1.z);
        val1[7] = fmaf(acc[7], di, bb1.w);
    }
    // softmax over 40 classes per quarter: sub 0..3 hold val0, sub 0 additionally val1
    float m = -INFINITY;
    if (g2 == 0) {
        #pragma unroll
        for (int k = 0; k < 8; k++) m = fmaxf(m, val0[k]);
    }
    if (sub == 0) {
        #pragma unroll
        for (int k = 0; k < 8; k++) m = fmaxf(m, val1[k]);
    }
    m = fmaxf(m, __shfl_xor(m, 1));
    m = fmaxf(m, __shfl_xor(m, 2));
    float ssum = 0.f;
    if (g2 == 0) {
        #pragma unroll
        for (int k = 0; k < 8; k++) ssum += expf(val0[k] - m);
    }
    if (sub == 0) {
        #pragma unroll
        for (int k = 0; k < 8; k++) ssum += expf(val1[k] - m);
    }
    ssum += __shfl_xor(ssum, 1);
    ssum += __shfl_xor(ssum, 2);
    if (g2 == 0) {
        float ls = m + logf(ssum);
        float4 r0 = make_float4(val0[0] - ls, val0[1] - ls, val0[2] - ls, val0[3] - ls);
        float4 r1 = make_float4(val0[4] - ls, val0[5] - ls, val0[6] - ls, val0[7] - ls);
        float4* orow = (float4*)(out + (size_t)i * NCLASS + fl * 8);
        orow[0] = r0;
        orow[1] = r1;
        if (sub == 0) {
            float4 r2 = make_float4(val1[0] - ls, val1[1] - ls, val1[2] - ls, val1[3] - ls);
            float4 r3 = make_float4(val1[4] - ls, val1[5] - ls, val1[6] - ls, val1[7] - ls);
            float4* orow1 = (float4*)(out + (size_t)i * NCLASS + 32);
            orow1[0] = r2;
            orow1[1] = r3;
        }
    }
}

extern "C" void kernel_launch(void* const* d_in, const int* in_sizes, int n_in,
                              void* d_out, int out_size, void* d_ws, size_t ws_size,
                              hipStream_t stream) {
    const float* x    = (const float*)d_in[0];
    const int*   ei   = (const int*)d_in[1];
    const float* W1   = (const float*)d_in[2];
    const float* b1   = (const float*)d_in[3];
    const float* W2   = (const float*)d_in[4];
    const float* b2   = (const float*)d_in[5];
    const float* mask = (const float*)d_in[6];
    float* out = (float*)d_out;

    const int* src = ei;
    const int* dst = ei + N_EDGES;

    char* ws = (char*)d_ws;
    size_t off = 0;
    __half* h1p    = (__half*)(ws + off); off += (size_t)NPAD * NHID * 2;      // 12.8 MB
    __half* h1h    = (__half*)(ws + off); off += (size_t)NPAD * NHID * 2;      // 12.8 MB
    int*    esrc   = (int*)   (ws + off); off += (size_t)NBUCK * CAP * 4 + 256;// 8.0 MB
    float*  dinv   = (float*) (ws + off); off += (size_t)NPAD * 4;
    int*   row_beg = (int*)   (ws + off); off += (size_t)NPAD * 4;
    int*   row_cnt = (int*)   (ws + off); off += (size_t)NPAD * 4;
    int*    gcur   = (int*)   (ws + off); off += 2048;
    __half* w1t    = (__half*)(ws + off); off += 128 * 256 * 2;                // 64 KB
    __half* w2t    = (__half*)(ws + off); off += 48 * 128 * 2;                 // 12 KB

    unsigned int* packed = (unsigned int*)h1p;  // binA/binB lifetime only
    __half* h2pl = h1h;                          // gemm2/agg2 lifetime (4.0 MB used)

    k_prep<<<196, 256, 0, stream>>>(W1, W2, w1t, w2t, gcur, dinv);
    k_binA<<<(N_EDGES + EPB - 1) / EPB, 256, 0, stream>>>(src, dst, gcur, packed);
    k_binB<<<NBUCK, 256, 0, stream>>>(gcur, packed, esrc, row_beg, row_cnt, dinv);

    k_gemm1<<<NPAD / 64, 256, 0, stream>>>(x, w1t, dinv, h1h);
    k_agg1<<<N_NODES / 2, 64, 0, stream>>>(h1h, dinv, row_beg, row_cnt, esrc, b1, mask, h1p);
    k_gemm2<<<NPAD / 64, 256, 0, stream>>>(h1p, w2t, dinv, h2pl);
    k_agg2<<<N_NODES / 4, 64, 0, stream>>>(h2pl, dinv, row_beg, row_cnt, esrc, b2, out);
}

// Round 14
// 254.554 us; speedup vs baseline: 7.8866x; 1.0181x over previous
//
#include <hip/hip_runtime.h>
#include <hip/hip_fp16.h>
#include <math.h>

#define N_NODES 50000
#define N_EDGES 1600000
#define NFEAT 256
#define NHID 128
#define NCLASS 40

#define NPAD 50048           // grid-rounded node count (dummy zero rows >= N_NODES)
#define DUMMY N_NODES        // index of a guaranteed-zero table row

#define BSHIFT 7
#define NBUCK 391            // ceil(50000 / 128)
#define CAP 5120             // per-bucket capacity (mean 4092)
#define EPB 4096             // edges per binA block -> 391 blocks

typedef _Float16 f16x8 __attribute__((ext_vector_type(8)));
typedef float f32x4 __attribute__((ext_vector_type(4)));
typedef float fv4 __attribute__((ext_vector_type(4)));      // nt-capable float4
typedef unsigned int uv4 __attribute__((ext_vector_type(4))); // nt-capable uint4

// ---------------- pass A: coarse binning by dst>>7 ----------------
__global__ __launch_bounds__(256) void k_binA(const int* __restrict__ src,
                                              const int* __restrict__ dst,
                                              int* __restrict__ gcur,
                                              unsigned int* __restrict__ packed) {
    __shared__ int lhist[NBUCK];
    __shared__ int lbase[NBUCK];
    __shared__ int lcur[NBUCK];
    int t = threadIdx.x;
    for (int i = t; i < NBUCK; i += 256) { lhist[i] = 0; lcur[i] = 0; }
    __syncthreads();
    int e0 = blockIdx.x * EPB;
    int e1 = min(e0 + EPB, N_EDGES);
    for (int e = e0 + t; e < e1; e += 256) {
        int b = dst[e] >> BSHIFT;
        atomicAdd(&lhist[b], 1);
    }
    __syncthreads();
    for (int i = t; i < NBUCK; i += 256)
        lbase[i] = atomicAdd(&gcur[i], lhist[i]);
    __syncthreads();
    for (int e = e0 + t; e < e1; e += 256) {
        int d = dst[e];
        int b = d >> BSHIFT;
        int r = atomicAdd(&lcur[b], 1);
        int pos = lbase[b] + r;
        if (pos < CAP)
            packed[(size_t)b * CAP + pos] =
                ((unsigned int)src[e] << BSHIFT) | (unsigned int)(d & 127);
    }
}

// ---------------- pass B: in-LDS fine sort per bucket + CSR metadata + dinv ----------------
__global__ __launch_bounds__(256) void k_binB(const int* __restrict__ gcur,
                                              const unsigned int* __restrict__ packed,
                                              int* __restrict__ esrc,
                                              int* __restrict__ row_beg,
                                              int* __restrict__ row_cnt,
                                              float* __restrict__ dinv) {
    __shared__ unsigned int sp[CAP];     // 20 KB
    __shared__ int hist[128];
    __shared__ int scan[128];
    __shared__ int cur[128];
    int b = blockIdx.x;
    int t = threadIdx.x;
    int cnt = min(gcur[b], CAP);
    if (t < 128) { hist[t] = 0; cur[t] = 0; }
    __syncthreads();
    const unsigned int* pin = packed + (size_t)b * CAP;
    for (int i = t; i < cnt; i += 256) {
        unsigned int w = pin[i];
        sp[i] = w;
        atomicAdd(&hist[w & 127], 1);
    }
    __syncthreads();
    if (t == 0) {
        int s = 0;
        for (int i = 0; i < 128; i++) { scan[i] = s; s += hist[i]; }
    }
    __syncthreads();
    for (int i = t; i < cnt; i += 256) {
        unsigned int w = sp[i];
        int dl = (int)(w & 127u);
        int r = atomicAdd(&cur[dl], 1);
        esrc[(size_t)b * CAP + scan[dl] + r] = (int)(w >> BSHIFT);
    }
    if (t < 128) {
        int node = b * 128 + t;
        if (node < N_NODES) {
            row_beg[node] = b * CAP + scan[t];
            row_cnt[node] = hist[t];
            dinv[node] = rsqrtf((float)(hist[t] + 1));
        }
    }
}

// ---------------- prep: W transposes to fp16 + gcur zero + dinv tail zero ----------------
__global__ __launch_bounds__(256) void k_prep(const float* __restrict__ W1,
                                              const float* __restrict__ W2,
                                              __half* __restrict__ w1t,
                                              __half* __restrict__ w2t,
                                              int* __restrict__ gcur,
                                              float* __restrict__ dinv) {
    int t = blockIdx.x * 256 + threadIdx.x;
    if (t < NBUCK) gcur[t] = 0;
    if (t >= N_NODES && t < NPAD) dinv[t] = 0.0f;   // dummy rows scale to zero
    if (t < 128 * 256) {
        int n = t >> 8, k = t & 255;
        w1t[t] = __float2half(W1[k * NHID + n]);
    }
    if (t < 48 * 128) {
        int n = t >> 7, k = t & 127;
        w2t[t] = __float2half(n < NCLASS ? W2[k * NCLASS + n] : 0.0f);
    }
}

// ---------------- GEMM1 (MFMA): h1h(fp16) = (x @ W1) * dinv[row]  (pre-scaled table) ----------------
#define G1_LDA 72
#define G1_LDB 72
#define G1_LDE 136
__global__ __launch_bounds__(256) void k_gemm1(const float* __restrict__ x,
                                               const __half* __restrict__ w1t,
                                               const float* __restrict__ dinv,
                                               __half* __restrict__ h1h) {
    __shared__ __half smem[64 * G1_LDA + 128 * G1_LDB];   // 27.6 KB
    __half* sA = smem;
    __half* sB = smem + 64 * G1_LDA;
    int t = threadIdx.x;
    int rbase = blockIdx.x * 64;
    int lane = t & 63, wv = t >> 6;
    int m = lane & 15, quad = lane >> 4;
    f32x4 acc[8];
    #pragma unroll
    for (int i = 0; i < 8; i++) acc[i] = (f32x4)0.0f;

    int arow = t >> 2, aseg = t & 3;
    int grow = rbase + arow;
    bool avalid = grow < N_NODES;
    int bn = t >> 1, bseg = t & 1;

    for (int k0 = 0; k0 < NFEAT; k0 += 64) {
        const float4* gs = (const float4*)(x + (size_t)grow * NFEAT + k0 + aseg * 16);
        __half* ad = sA + arow * G1_LDA + aseg * 16;
        #pragma unroll
        for (int i = 0; i < 4; i++) {
            float4 v = avalid ? gs[i] : make_float4(0.f, 0.f, 0.f, 0.f);
            __half2 h0 = __float22half2_rn(make_float2(v.x, v.y));
            __half2 h1 = __float22half2_rn(make_float2(v.z, v.w));
            uint2 st;
            st.x = __builtin_bit_cast(unsigned int, h0);
            st.y = __builtin_bit_cast(unsigned int, h1);
            *(uint2*)(ad + i * 4) = st;
        }
        const uint4* ws4 = (const uint4*)(w1t + bn * NFEAT + k0 + bseg * 32);
        uint4* bd = (uint4*)(sB + bn * G1_LDB + bseg * 32);
        #pragma unroll
        for (int i = 0; i < 4; i++) bd[i] = ws4[i];
        __syncthreads();
        #pragma unroll
        for (int kk = 0; kk < 64; kk += 32) {
            f16x8 af = *(const f16x8*)(sA + (wv * 16 + m) * G1_LDA + kk + quad * 8);
            #pragma unroll
            for (int t8 = 0; t8 < 8; t8++) {
                f16x8 bf = *(const f16x8*)(sB + (t8 * 16 + m) * G1_LDB + kk + quad * 8);
                acc[t8] = __builtin_amdgcn_mfma_f32_16x16x32_f16(af, bf, acc[t8], 0, 0, 0);
            }
        }
        __syncthreads();
    }
    // pre-scale each output row by dinv[row] while packing (rows >= N_NODES have dinv=0 -> zero rows)
    float di4[4];
    #pragma unroll
    for (int r = 0; r < 4; r++) di4[r] = dinv[rbase + wv * 16 + quad * 4 + r];
    __half* eb = smem;
    #pragma unroll
    for (int t8 = 0; t8 < 8; t8++) {
        #pragma unroll
        for (int r = 0; r < 4; r++)
            eb[(wv * 16 + quad * 4 + r) * G1_LDE + t8 * 16 + m] = __float2half(acc[t8][r] * di4[r]);
    }
    __syncthreads();
    {   // unconditional store: grid covers exactly NPAD rows; dummy rows are zeros
        const uint4* es = (const uint4*)(eb + arow * G1_LDE + aseg * 32);
        uint4* od = (uint4*)(h1h + (size_t)grow * NHID + aseg * 32);
        #pragma unroll
        for (int i = 0; i < 4; i++) od[i] = es[i];
    }
}

// ---------------- GEMM2 (MFMA): h2 planes = (h1p @ W2) * dinv[row] ----------------
// planeA: cls 0..31 as 64B rows (3.2MB); planeB: cls 32..39 as 16B rows (0.8MB)
#define G2_LDA 136
#define G2_LDB 136
#define G2_LDE 72
__global__ __launch_bounds__(256) void k_gemm2(const __half* __restrict__ h1p,
                                               const __half* __restrict__ w2t,
                                               const float* __restrict__ dinv,
                                               __half* __restrict__ h2pl) {
    __shared__ __half smem[64 * G2_LDA + 48 * G2_LDB];  // 30.5 KB
    __half* sA = smem;
    __half* sB = smem + 64 * G2_LDA;
    int t = threadIdx.x;
    int rbase = blockIdx.x * 64;
    int lane = t & 63, wv = t >> 6;
    int m = lane & 15, quad = lane >> 4;
    f32x4 acc[3];
    #pragma unroll
    for (int i = 0; i < 3; i++) acc[i] = (f32x4)0.0f;

    int arow = t >> 2, aseg = t & 3;
    int grow = rbase + arow;
    bool avalid = grow < N_NODES;

    #pragma unroll
    for (int i = 0; i < 3; i++) {
        int idx = t + i * 256;
        int n = idx >> 4, seg = idx & 15;
        *(uint4*)(sB + n * G2_LDB + seg * 8) = *(const uint4*)(w2t + n * NHID + seg * 8);
    }
    {
        const uint4* gs = (const uint4*)(h1p + (size_t)grow * NHID + aseg * 32);
        uint4* ad = (uint4*)(sA + arow * G2_LDA + aseg * 32);
        uint4 z; z.x = z.y = z.z = z.w = 0;
        #pragma unroll
        for (int i = 0; i < 4; i++) ad[i] = avalid ? gs[i] : z;
    }
    __syncthreads();
    #pragma unroll
    for (int kk = 0; kk < 128; kk += 32) {
        f16x8 af = *(const f16x8*)(sA + (wv * 16 + m) * G2_LDA + kk + quad * 8);
        #pragma unroll
        for (int t3 = 0; t3 < 3; t3++) {
            f16x8 bf = *(const f16x8*)(sB + (t3 * 16 + m) * G2_LDB + kk + quad * 8);
            acc[t3] = __builtin_amdgcn_mfma_f32_16x16x32_f16(af, bf, acc[t3], 0, 0, 0);
        }
    }
    __syncthreads();
    float di4[4];
    #pragma unroll
    for (int r = 0; r < 4; r++) di4[r] = dinv[rbase + wv * 16 + quad * 4 + r];
    __half* eb = smem;
    #pragma unroll
    for (int t3 = 0; t3 < 3; t3++) {
        #pragma unroll
        for (int r = 0; r < 4; r++)
            eb[(wv * 16 + quad * 4 + r) * G2_LDE + t3 * 16 + m] = __float2half(acc[t3][r] * di4[r]);
    }
    __syncthreads();
    __half* pA = h2pl;
    __half* pB = h2pl + (size_t)NPAD * 32;
    #pragma unroll
    for (int i = 0; i < 2; i++) {
        int idx = t + i * 256;
        int row = idx >> 3, seg = idx & 7;
        int gr = rbase + row;   // unconditional: dummy rows store zeros (acc=0, di=0)
        if (seg <= 4) {
            uint4 v = *(const uint4*)(eb + row * G2_LDE + seg * 8);
            if (seg < 4) ((uint4*)pA)[(size_t)gr * 4 + seg] = v;
            else        ((uint4*)pB)[gr] = v;
        }
    }
}

__device__ __forceinline__ void acc8f(float* acc, uint4 v, float d) {
    float2 a0 = __half22float2(__builtin_bit_cast(__half2, v.x));
    float2 a1 = __half22float2(__builtin_bit_cast(__half2, v.y));
    float2 a2 = __half22float2(__builtin_bit_cast(__half2, v.z));
    float2 a3 = __half22float2(__builtin_bit_cast(__half2, v.w));
    acc[0] = fmaf(a0.x, d, acc[0]); acc[1] = fmaf(a0.y, d, acc[1]);
    acc[2] = fmaf(a1.x, d, acc[2]); acc[3] = fmaf(a1.y, d, acc[3]);
    acc[4] = fmaf(a2.x, d, acc[4]); acc[5] = fmaf(a2.y, d, acc[5]);
    acc[6] = fmaf(a3.x, d, acc[6]); acc[7] = fmaf(a3.y, d, acc[7]);
}

// ---------------- agg1: 2 nodes/wave (32 lanes each), 8-deep gathers (FROZEN, at request floor) ----------------
__global__ __launch_bounds__(64) void k_agg1(const __half* __restrict__ h1h,
                                             const float* __restrict__ dinv,
                                             const int* __restrict__ row_beg,
                                             const int* __restrict__ row_cnt,
                                             const int* __restrict__ esrc,
                                             const float* __restrict__ b1,
                                             const float* __restrict__ mask,
                                             __half* __restrict__ h1p) {
    int lane = threadIdx.x;
    int h = lane >> 5;        // node half (0/1)
    int sub = lane & 31;
    int i = blockIdx.x * 2 + h;   // N_NODES = 2*25000 exactly
    int g = sub >> 4;         // 2 edge groups per half
    int fl = sub & 15;        // 16B chunk of the 256B row
    const uint4* hv4 = (const uint4*)h1h;
    float di = dinv[i];
    __half2 hacc[4];
    __half2 hz = __half2half2(__float2half(0.0f));
    hacc[0] = hz; hacc[1] = hz; hacc[2] = hz; hacc[3] = hz;
    int s0 = row_beg[i], cnt = row_cnt[i];
    for (int base = 0; base < cnt; base += 32) {
        int idx = base + sub;
        int sv = (idx < cnt) ? __builtin_nontemporal_load(&esrc[s0 + idx]) : DUMMY;
        int n = min(32, cnt - base);
        int nr = (n + 15) & ~15;
        for (int j = 0; j < nr; j += 16) {
            int ss[8]; uint4 vv[8];
            #pragma unroll
            for (int k = 0; k < 8; k++) ss[k] = __shfl(sv, h * 32 + j + 2 * k + g);
            #pragma unroll
            for (int k = 0; k < 8; k++) vv[k] = hv4[(size_t)ss[k] * 16 + fl];
            #pragma unroll
            for (int k = 0; k < 8; k++) {
                hacc[0] = __hadd2(hacc[0], __builtin_bit_cast(__half2, vv[k].x));
                hacc[1] = __hadd2(hacc[1], __builtin_bit_cast(__half2, vv[k].y));
                hacc[2] = __hadd2(hacc[2], __builtin_bit_cast(__half2, vv[k].z));
                hacc[3] = __hadd2(hacc[3], __builtin_bit_cast(__half2, vv[k].w));
            }
        }
    }
    // reduce across the 2 edge groups (stride 16, stays within half)
    #pragma unroll
    for (int r = 0; r < 4; r++) {
        unsigned int u = __shfl_xor(__builtin_bit_cast(unsigned int, hacc[r]), 16);
        hacc[r] = __hadd2(hacc[r], __builtin_bit_cast(__half2, u));
    }
    if (g == 0) {   // sub 0..15 of each half
        float acc[8];
        #pragma unroll
        for (int r = 0; r < 4; r++) {
            float2 f = __half22float2(hacc[r]);
            acc[2 * r] = f.x; acc[2 * r + 1] = f.y;
        }
        uint4 sv4 = hv4[(size_t)i * 16 + fl];      // self row (already *dinv[i])
        acc8f(acc, sv4, 1.0f);
        float4 bb0 = ((const float4*)b1)[fl * 2];
        float4 bb1 = ((const float4*)b1)[fl * 2 + 1];
        const fv4* mrow = (const fv4*)(mask + (size_t)i * NHID);
        fv4 mm0 = __builtin_nontemporal_load(&mrow[fl * 2]);
        fv4 mm1 = __builtin_nontemporal_load(&mrow[fl * 2 + 1]);
        float o0 = fmaxf(fmaf(acc[0], di, bb0.x), 0.f) * mm0[0];
        float o1 = fmaxf(fmaf(acc[1], di, bb0.y), 0.f) * mm0[1];
        float o2 = fmaxf(fmaf(acc[2], di, bb0.z), 0.f) * mm0[2];
        float o3 = fmaxf(fmaf(acc[3], di, bb0.w), 0.f) * mm0[3];
        float o4 = fmaxf(fmaf(acc[4], di, bb1.x), 0.f) * mm1[0];
        float o5 = fmaxf(fmaf(acc[5], di, bb1.y), 0.f) * mm1[1];
        float o6 = fmaxf(fmaf(acc[6], di, bb1.z), 0.f) * mm1[2];
        float o7 = fmaxf(fmaf(acc[7], di, bb1.w), 0.f) * mm1[3];
        __half2 p0 = __float22half2_rn(make_float2(o0, o1));
        __half2 p1 = __float22half2_rn(make_float2(o2, o3));
        __half2 p2 = __float22half2_rn(make_float2(o4, o5));
        __half2 p3 = __float22half2_rn(make_float2(o6, o7));
        uv4 st;
        st[0] = __builtin_bit_cast(unsigned int, p0);
        st[1] = __builtin_bit_cast(unsigned int, p1);
        st[2] = __builtin_bit_cast(unsigned int, p2);
        st[3] = __builtin_bit_cast(unsigned int, p3);
        __builtin_nontemporal_store(st, &((uv4*)h1p)[(size_t)i * 16 + fl]);
    }
}

// ---------------- agg2: 8 nodes/wave (8 lanes each), slim planes, + log_softmax ----------------
// per eighth-wave: 2 edge-slots (g2) x 4 chunks (fl) for planeA; per-lane planeB.
__global__ __launch_bounds__(64) void k_agg2(const __half* __restrict__ h2pl,
                                             const float* __restrict__ dinv,
                                             const int* __restrict__ row_beg,
                                             const int* __restrict__ row_cnt,
                                             const int* __restrict__ esrc,
                                             const float* __restrict__ b2,
                                             float* __restrict__ out) {
    int lane = threadIdx.x;
    int h = lane >> 3;        // node eighth (0..7)
    int sub = lane & 7;
    int i = blockIdx.x * 8 + h;   // N_NODES = 8*6250 exactly
    int g2 = sub >> 2;        // 2 edge slots per eighth
    int fl = sub & 3;         // 16B chunk of 64B planeA row
    const uint4* pA = (const uint4*)h2pl;
    const uint4* pB = (const uint4*)(h2pl + (size_t)NPAD * 32);
    float di = dinv[i];
    __half2 a0[4], a1[4];
    __half2 hz = __half2half2(__float2half(0.0f));
    #pragma unroll
    for (int r = 0; r < 4; r++) { a0[r] = hz; a1[r] = hz; }
    int s0 = row_beg[i], cnt = row_cnt[i];
    for (int base = 0; base < cnt; base += 8) {
        int idx = base + sub;
        int sv = (idx < cnt) ? __builtin_nontemporal_load(&esrc[s0 + idx]) : DUMMY;
        // planeB: one edge per lane (16B row, zeros at DUMMY)
        uint4 v1 = pB[sv];
        a1[0] = __hadd2(a1[0], __builtin_bit_cast(__half2, v1.x));
        a1[1] = __hadd2(a1[1], __builtin_bit_cast(__half2, v1.y));
        a1[2] = __hadd2(a1[2], __builtin_bit_cast(__half2, v1.z));
        a1[3] = __hadd2(a1[3], __builtin_bit_cast(__half2, v1.w));
        // planeA: 2 slots x 4 j-steps = 8 edges per batch
        int n = min(8, cnt - base);
        int nr = (n + 1) & ~1;
        for (int j = 0; j < nr; j += 2) {
            int ss = __shfl(sv, h * 8 + j + g2);
            uint4 vv = pA[(size_t)ss * 4 + fl];
            a0[0] = __hadd2(a0[0], __builtin_bit_cast(__half2, vv.x));
            a0[1] = __hadd2(a0[1], __builtin_bit_cast(__half2, vv.y));
            a0[2] = __hadd2(a0[2], __builtin_bit_cast(__half2, vv.z));
            a0[3] = __hadd2(a0[3], __builtin_bit_cast(__half2, vv.w));
        }
    }
    // a1: eighth reduce (strides 1,2,4); a0: slot reduce (stride 4)
    #pragma unroll
    for (int d = 1; d <= 4; d <<= 1) {
        #pragma unroll
        for (int r = 0; r < 4; r++) {
            unsigned int u = __shfl_xor(__builtin_bit_cast(unsigned int, a1[r]), d);
            a1[r] = __hadd2(a1[r], __builtin_bit_cast(__half2, u));
            if (d == 4) {
                unsigned int u0 = __shfl_xor(__builtin_bit_cast(unsigned int, a0[r]), d);
                a0[r] = __hadd2(a0[r], __builtin_bit_cast(__half2, u0));
            }
        }
    }
    float val0[8], val1[8];
    if (g2 == 0) {   // sub 0..3: classes [fl*8, fl*8+8)
        float acc[8];
        #pragma unroll
        for (int r = 0; r < 4; r++) {
            float2 f = __half22float2(a0[r]);
            acc[2 * r] = f.x; acc[2 * r + 1] = f.y;
        }
        uint4 s4 = pA[(size_t)i * 4 + fl];          // self (pre-scaled)
        acc8f(acc, s4, 1.0f);
        float4 bb0 = *(const float4*)(b2 + fl * 8);
        float4 bb1 = *(const float4*)(b2 + fl * 8 + 4);
        val0[0] = fmaf(acc[0], di, bb0.x);
        val0[1] = fmaf(acc[1], di, bb0.y);
        val0[2] = fmaf(acc[2], di, bb0.z);
        val0[3] = fmaf(acc[3], di, bb0.w);
        val0[4] = fmaf(acc[4], di, bb1.x);
        val0[5] = fmaf(acc[5], di, bb1.y);
        val0[6] = fmaf(acc[6], di, bb1.z);
        val0[7] = fmaf(acc[7], di, bb1.w);
    }
    if (sub == 0) {  // classes 32..39
        float acc[8];
        #pragma unroll
        for (int r = 0; r < 4; r++) {
            float2 f = __half22float2(a1[r]);
            acc[2 * r] = f.x; acc[2 * r + 1] = f.y;
        }
        acc8f(acc, pB[i], 1.0f);                    // self (pre-scaled)
        float4 bb0 = *(const float4*)(b2 + 32);
        float4 bb1 = *(const float4*)(b2 + 36);
        val1[0] = fmaf(acc[0], di, bb0.x);
        val1[1] = fmaf(acc[1], di, bb0.y);
        val1[2] = fmaf(acc[2], di, bb0.z);
        val1[3] = fmaf(acc[3], di, bb0.w);
        val1[4] = fmaf(acc[4], di, bb1.x);
        val1[5] = fmaf(acc[5], di, bb1.y);
        val1[6] = fmaf(acc[6], di, bb1.z);
        val1[7] = fmaf(acc[7], di, bb1.w);
    }
    // softmax over 40 classes per eighth: sub 0..3 hold val0, sub 0 additionally val1
    float m = -INFINITY;
    if (g2 == 0) {
        #pragma unroll
        for (int k = 0; k < 8; k++) m = fmaxf(m, val0[k]);
    }
    if (sub == 0) {
        #pragma unroll
        for (int k = 0; k < 8; k++) m = fmaxf(m, val1[k]);
    }
    m = fmaxf(m, __shfl_xor(m, 1));
    m = fmaxf(m, __shfl_xor(m, 2));
    float ssum = 0.f;
    if (g2 == 0) {
        #pragma unroll
        for (int k = 0; k < 8; k++) ssum += expf(val0[k] - m);
    }
    if (sub == 0) {
        #pragma unroll
        for (int k = 0; k < 8; k++) ssum += expf(val1[k] - m);
    }
    ssum += __shfl_xor(ssum, 1);
    ssum += __shfl_xor(ssum, 2);
    if (g2 == 0) {
        float ls = m + logf(ssum);
        float4 r0 = make_float4(val0[0] - ls, val0[1] - ls, val0[2] - ls, val0[3] - ls);
        float4 r1 = make_float4(val0[4] - ls, val0[5] - ls, val0[6] - ls, val0[7] - ls);
        float4* orow = (float4*)(out + (size_t)i * NCLASS + fl * 8);
        orow[0] = r0;
        orow[1] = r1;
        if (sub == 0) {
            float4 r2 = make_float4(val1[0] - ls, val1[1] - ls, val1[2] - ls, val1[3] - ls);
            float4 r3 = make_float4(val1[4] - ls, val1[5] - ls, val1[6] - ls, val1[7] - ls);
            float4* orow1 = (float4*)(out + (size_t)i * NCLASS + 32);
            orow1[0] = r2;
            orow1[1] = r3;
        }
    }
}

extern "C" void kernel_launch(void* const* d_in, const int* in_sizes, int n_in,
                              void* d_out, int out_size, void* d_ws, size_t ws_size,
                              hipStream_t stream) {
    const float* x    = (const float*)d_in[0];
    const int*   ei   = (const int*)d_in[1];
    const float* W1   = (const float*)d_in[2];
    const float* b1   = (const float*)d_in[3];
    const float* W2   = (const float*)d_in[4];
    const float* b2   = (const float*)d_in[5];
    const float* mask = (const float*)d_in[6];
    float* out = (float*)d_out;

    const int* src = ei;
    const int* dst = ei + N_EDGES;

    char* ws = (char*)d_ws;
    size_t off = 0;
    __half* h1p    = (__half*)(ws + off); off += (size_t)NPAD * NHID * 2;      // 12.8 MB
    __half* h1h    = (__half*)(ws + off); off += (size_t)NPAD * NHID * 2;      // 12.8 MB
    int*    esrc   = (int*)   (ws + off); off += (size_t)NBUCK * CAP * 4 + 256;// 8.0 MB
    float*  dinv   = (float*) (ws + off); off += (size_t)NPAD * 4;
    int*   row_beg = (int*)   (ws + off); off += (size_t)NPAD * 4;
    int*   row_cnt = (int*)   (ws + off); off += (size_t)NPAD * 4;
    int*    gcur   = (int*)   (ws + off); off += 2048;
    __half* w1t    = (__half*)(ws + off); off += 128 * 256 * 2;                // 64 KB
    __half* w2t    = (__half*)(ws + off); off += 48 * 128 * 2;                 // 12 KB

    unsigned int* packed = (unsigned int*)h1p;  // binA/binB lifetime only
    __half* h2pl = h1h;                          // gemm2/agg2 lifetime (4.0 MB used)

    k_prep<<<196, 256, 0, stream>>>(W1, W2, w1t, w2t, gcur, dinv);
    k_binA<<<(N_EDGES + EPB - 1) / EPB, 256, 0, stream>>>(src, dst, gcur, packed);
    k_binB<<<NBUCK, 256, 0, stream>>>(gcur, packed, esrc, row_beg, row_cnt, dinv);

    k_gemm1<<<NPAD / 64, 256, 0, stream>>>(x, w1t, dinv, h1h);
    k_agg1<<<N_NODES / 2, 64, 0, stream>>>(h1h, dinv, row_beg, row_cnt, esrc, b1, mask, h1p);
    k_gemm2<<<NPAD / 64, 256, 0, stream>>>(h1p, w2t, dinv, h2pl);
    k_agg2<<<N_NODES / 8, 64, 0, stream>>>(h2pl, dinv, row_beg, row_cnt, esrc, b2, out);
}